// Round 3
// baseline (3765.763 us; speedup 1.0000x reference)
//
#include <hip/hip_runtime.h>
#include <hip/hip_bf16.h>
#include <cstdint>
#include <cmath>

typedef __hip_bfloat16 bf16;

__device__ __forceinline__ float b2f(bf16 v) { return __bfloat162float(v); }
__device__ __forceinline__ bf16 f2b(float v) { return __float2bfloat16(v); }

constexpr int Nn = 2048;    // nodes
constexpr int Bb = 64;      // batch
constexpr int Dd = 16;      // embedding dim
constexpr int Cc = 66;      // DIN + H
constexpr int Hh = 64;      // hidden
constexpr int BC = Bb * Cc; // 4224

// dtype-flagged scalar load: f32 ? fp32 : bf16
__device__ __forceinline__ float ldf(const void* p, size_t i, int f32) {
  return f32 ? ((const float*)p)[i] : b2f(((const bf16*)p)[i]);
}

// load 8 consecutive bf16 (16B aligned) -> 8 floats
__device__ __forceinline__ void load8f(const bf16* p, float f[8]) {
  uint4 v = *(const uint4*)p;
  unsigned w[4] = {v.x, v.y, v.z, v.w};
#pragma unroll
  for (int i = 0; i < 4; i++) {
    f[2 * i]     = __uint_as_float(w[i] << 16);
    f[2 * i + 1] = __uint_as_float(w[i] & 0xffff0000u);
  }
}

// pack 8 floats -> 8 bf16 (RN) as uint4
__device__ __forceinline__ uint4 pack8(const float f[8]) {
  unsigned w[4];
#pragma unroll
  for (int i = 0; i < 4; i++) {
    union { bf16 h; unsigned short u; } lo, hi;
    lo.h = f2b(f[2 * i]);
    hi.h = f2b(f[2 * i + 1]);
    w[i] = (unsigned)lo.u | ((unsigned)hi.u << 16);
  }
  return make_uint4(w[0], w[1], w[2], w[3]);
}

// ---------------------------------------------------------------------------
// Dtype probe: if E is fp32, low 16 bits of each word are random mantissa
// (exponent-pattern rate ~10%); if bf16-pairs, low half is a bf16 N(0,1)
// value (rate ~100%). flag=1 -> inputs are fp32.
// ---------------------------------------------------------------------------
__global__ void detect_kernel(const void* __restrict__ E, int* __restrict__ flag) {
  if (threadIdx.x == 0) {
    const unsigned* p = (const unsigned*)E;
    int hits = 0;
    for (int i = 0; i < 64; i++) {
      unsigned ex = (p[i] >> 7) & 0xFF;   // exponent field of low 16 bits
      hits += (ex >= 100 && ex <= 140) ? 1 : 0;
    }
    *flag = (hits < 32) ? 1 : 0;
  }
}

// ---------------------------------------------------------------------------
// A[n,m] = softmax_m(relu(E[n]·E[m])) * mask[n,m]  (+ optional re-softmax)
// One block per row n; whole row in LDS. Output bf16.
// ---------------------------------------------------------------------------
__global__ __launch_bounds__(256) void support_kernel(
    const void* __restrict__ E, const void* __restrict__ mask,
    const int* __restrict__ normalize, const int* __restrict__ flag,
    bf16* __restrict__ A) {
  __shared__ float row[Nn];
  __shared__ float red[256];
  __shared__ float en[Dd];
  int f = *flag;
  int n = blockIdx.x;
  int t = threadIdx.x;
  if (t < Dd) en[t] = ldf(E, (size_t)n * Dd + t, f);
  __syncthreads();

  float lmax = -1e30f;
  for (int m = t; m < Nn; m += 256) {
    float s = 0.f;
#pragma unroll
    for (int d = 0; d < Dd; d++) s += en[d] * ldf(E, (size_t)m * Dd + d, f);
    s = fmaxf(s, 0.f);
    row[m] = s;
    lmax = fmaxf(lmax, s);
  }
  red[t] = lmax; __syncthreads();
  for (int w = 128; w > 0; w >>= 1) { if (t < w) red[t] = fmaxf(red[t], red[t + w]); __syncthreads(); }
  float mx = red[0]; __syncthreads();

  float lsum = 0.f;
  for (int m = t; m < Nn; m += 256) { float e = expf(row[m] - mx); row[m] = e; lsum += e; }
  red[t] = lsum; __syncthreads();
  for (int w = 128; w > 0; w >>= 1) { if (t < w) red[t] += red[t + w]; __syncthreads(); }
  float inv = 1.f / red[0]; __syncthreads();

  for (int m = t; m < Nn; m += 256)
    row[m] = row[m] * inv * ldf(mask, (size_t)n * Nn + m, f);

  if (*normalize != 0) {
    __syncthreads();
    lmax = -1e30f;
    for (int m = t; m < Nn; m += 256) lmax = fmaxf(lmax, row[m]);
    red[t] = lmax; __syncthreads();
    for (int w = 128; w > 0; w >>= 1) { if (t < w) red[t] = fmaxf(red[t], red[t + w]); __syncthreads(); }
    mx = red[0]; __syncthreads();
    lsum = 0.f;
    for (int m = t; m < Nn; m += 256) { float e = expf(row[m] - mx); row[m] = e; lsum += e; }
    red[t] = lsum; __syncthreads();
    for (int w = 128; w > 0; w >>= 1) { if (t < w) red[t] += red[t + w]; __syncthreads(); }
    inv = 1.f / red[0]; __syncthreads();
    for (int m = t; m < Nn; m += 256) row[m] *= inv;
  }
  __syncthreads();
  for (int m = t; m < Nn; m += 256) A[(size_t)n * Nn + m] = f2b(row[m]);
}

// ---------------------------------------------------------------------------
// X[m, b*66+c] = concat(x, state), layout (N x B*C), bf16 store
// ---------------------------------------------------------------------------
__global__ __launch_bounds__(256) void build_x_kernel(
    const void* __restrict__ x, const void* __restrict__ state,
    const int* __restrict__ flag, bf16* __restrict__ X) {
  int f = *flag;
  int idx = blockIdx.x * 256 + threadIdx.x;
  if (idx >= Nn * BC) return;
  int m = idx / BC;
  int j = idx - m * BC;
  int b = j / Cc;
  int c = j - b * Cc;
  float v = (c < 2) ? ldf(x, ((size_t)b * Nn + m) * 2 + c, f)
                    : ldf(state, ((size_t)b * Nn + m) * Hh + (c - 2), f);
  X[idx] = f2b(v);
}

// ---------------------------------------------------------------------------
// bf16 GEMM (fp32 accumulate): C[M x N] = A[M x K] @ B[K x N]
// tiles 128x128x16, 8x8 per thread
// ---------------------------------------------------------------------------
__global__ __launch_bounds__(256) void gemm_bf16(
    const bf16* __restrict__ A, const bf16* __restrict__ B, bf16* __restrict__ C,
    int M, int N, int K) {
  __shared__ float As[16][132];
  __shared__ float Bs[16][132];
  int t = threadIdx.x;
  int tx = t & 15, ty = t >> 4;
  int bm = blockIdx.y * 128, bn = blockIdx.x * 128;
  float acc[8][8] = {};

  for (int k0 = 0; k0 < K; k0 += 16) {
    {
      int row = t >> 1;   // 0..127
      int ch  = t & 1;    // which 8-wide k chunk
      float f[8];
      load8f(&A[(size_t)(bm + row) * K + k0 + ch * 8], f);
#pragma unroll
      for (int j = 0; j < 8; j++) As[ch * 8 + j][row] = f[j];
    }
    {
      int k   = t >> 4;   // 0..15
      int seg = t & 15;   // 0..15 (8 cols each)
      float f[8];
      load8f(&B[(size_t)(k0 + k) * N + bn + seg * 8], f);
      *(float4*)&Bs[k][seg * 8]     = make_float4(f[0], f[1], f[2], f[3]);
      *(float4*)&Bs[k][seg * 8 + 4] = make_float4(f[4], f[5], f[6], f[7]);
    }
    __syncthreads();
#pragma unroll
    for (int k = 0; k < 16; k++) {
      float a[8], b[8];
      *(float4*)&a[0] = *(const float4*)&As[k][ty * 8];
      *(float4*)&a[4] = *(const float4*)&As[k][ty * 8 + 4];
      *(float4*)&b[0] = *(const float4*)&Bs[k][tx * 8];
      *(float4*)&b[4] = *(const float4*)&Bs[k][tx * 8 + 4];
#pragma unroll
      for (int i = 0; i < 8; i++)
#pragma unroll
        for (int j = 0; j < 8; j++)
          acc[i][j] = fmaf(a[i], b[j], acc[i][j]);
    }
    __syncthreads();
  }
#pragma unroll
  for (int i = 0; i < 8; i++) {
    uint4 v = pack8(acc[i]);
    *(uint4*)&C[(size_t)(bm + ty * 8 + i) * N + bn + tx * 8] = v;
  }
}

// ---------------------------------------------------------------------------
// Gate: z_r = sigmoid(per-node einsum + bias). Writes r into d_out (output
// dtype) and candidate into Xc (aliases X: row-n reads complete before the
// barrier, writes after; blocks only touch their own row). One block/node.
// ---------------------------------------------------------------------------
__global__ __launch_bounds__(256) void gate_kernel(
    bf16* Xc, const bf16* __restrict__ Y1, const bf16* __restrict__ Y2,
    const void* __restrict__ E, const void* __restrict__ W, const void* __restrict__ bp,
    const void* __restrict__ x, const void* __restrict__ state,
    const int* __restrict__ flag, void* Rout) {
  __shared__ float xg[Bb][198];
  __shared__ float en[Dd];
  int f = *flag;
  int n = blockIdx.x;
  int t = threadIdx.x;
  if (t < Dd) en[t] = ldf(E, (size_t)n * Dd + t, f);
  const bf16* Xr  = Xc + (size_t)n * BC;
  const bf16* Y1r = Y1 + (size_t)n * BC;
  const bf16* Y2r = Y2 + (size_t)n * BC;
  for (int j = t; j < BC; j += 256) {
    int b = j / Cc, i = j - (j / Cc) * Cc;
    float xv = b2f(Xr[j]);
    xg[b][i]       = xv;                        // k=0: identity
    xg[b][66 + i]  = b2f(Y1r[j]);               // k=1: A@x
    xg[b][132 + i] = 2.f * b2f(Y2r[j]) - xv;    // k=2: (2A^2-I)@x
  }
  __syncthreads();

  int o = t & 127;   // output channel 0..127
  int bg = t >> 7;   // batch half
  float acc[32] = {};
  for (int ki = 0; ki < 198; ki++) {
    float w = 0.f;
#pragma unroll
    for (int d = 0; d < Dd; d++) w += en[d] * ldf(W, (size_t)(d * 198 + ki) * 128 + o, f);
#pragma unroll
    for (int bi = 0; bi < 32; bi++) acc[bi] = fmaf(w, xg[bg * 32 + bi][ki], acc[bi]);
  }
  float bias = 0.f;
#pragma unroll
  for (int d = 0; d < Dd; d++) bias += en[d] * ldf(bp, (size_t)d * 128 + o, f);

#pragma unroll
  for (int bi = 0; bi < 32; bi++) {
    int b = bg * 32 + bi;
    float v = 1.f / (1.f + expf(-(acc[bi] + bias)));
    if (o < 64) {  // z -> candidate = z * state
      float s = ldf(state, ((size_t)b * Nn + n) * Hh + o, f);
      Xc[(size_t)n * BC + b * Cc + 2 + o] = f2b(v * s);
    } else {       // r -> parked in d_out (output dtype)
      size_t idx = ((size_t)b * Nn + n) * Hh + (o - 64);
      if (f) ((float*)Rout)[idx] = v; else ((bf16*)Rout)[idx] = f2b(v);
    }
  }
  if (t < 128) {   // candidate x-part
    int b = t >> 1, c = t & 1;
    Xc[(size_t)n * BC + b * Cc + c] = f2b(ldf(x, ((size_t)b * Nn + n) * 2 + c, f));
  }
}

// ---------------------------------------------------------------------------
// Update: hc = tanh(...); out = r*state + (1-r)*hc. Reads r from `out`, then
// the same thread overwrites the same element — safe.
// ---------------------------------------------------------------------------
__global__ __launch_bounds__(256) void update_kernel(
    const bf16* __restrict__ Xc, const bf16* __restrict__ Y1, const bf16* __restrict__ Y2,
    const void* __restrict__ E, const void* __restrict__ W, const void* __restrict__ bp,
    const void* __restrict__ state, const int* __restrict__ flag, void* out) {
  __shared__ float xg[Bb][198];
  __shared__ float en[Dd];
  int f = *flag;
  int n = blockIdx.x;
  int t = threadIdx.x;
  if (t < Dd) en[t] = ldf(E, (size_t)n * Dd + t, f);
  const bf16* Xr  = Xc + (size_t)n * BC;
  const bf16* Y1r = Y1 + (size_t)n * BC;
  const bf16* Y2r = Y2 + (size_t)n * BC;
  for (int j = t; j < BC; j += 256) {
    int b = j / Cc, i = j - (j / Cc) * Cc;
    float xv = b2f(Xr[j]);
    xg[b][i]       = xv;
    xg[b][66 + i]  = b2f(Y1r[j]);
    xg[b][132 + i] = 2.f * b2f(Y2r[j]) - xv;
  }
  __syncthreads();

  int o = t & 63;
  int bg = t >> 6;   // 0..3
  float acc[16] = {};
  for (int ki = 0; ki < 198; ki++) {
    float w = 0.f;
#pragma unroll
    for (int d = 0; d < Dd; d++) w += en[d] * ldf(W, (size_t)(d * 198 + ki) * 64 + o, f);
#pragma unroll
    for (int bi = 0; bi < 16; bi++) acc[bi] = fmaf(w, xg[bg * 16 + bi][ki], acc[bi]);
  }
  float bias = 0.f;
#pragma unroll
  for (int d = 0; d < Dd; d++) bias += en[d] * ldf(bp, (size_t)d * 64 + o, f);

#pragma unroll
  for (int bi = 0; bi < 16; bi++) {
    int b = bg * 16 + bi;
    size_t idx = ((size_t)b * Nn + n) * Hh + o;
    float hc = tanhf(acc[bi] + bias);
    float r = f ? ((const float*)out)[idx] : b2f(((const bf16*)out)[idx]);
    float s = ldf(state, idx, f);
    float v = r * s + (1.f - r) * hc;
    if (f) ((float*)out)[idx] = v; else ((bf16*)out)[idx] = f2b(v);
  }
}

// ---------------------------------------------------------------------------
extern "C" void kernel_launch(void* const* d_in, const int* in_sizes, int n_in,
                              void* d_out, int out_size, void* d_ws, size_t ws_size,
                              hipStream_t stream) {
  const void* x     = d_in[0];
  const void* state = d_in[1];
  const void* E     = d_in[2];
  const void* mask  = d_in[3];
  const void* gW    = d_in[4];
  const void* gb    = d_in[5];
  const void* uW    = d_in[6];
  const void* ub    = d_in[7];
  const int* normalize = (const int*)d_in[8];

  // Workspace layout (bytes): flag(16) | A bf16 8.39MB | X bf16 17.3MB |
  // Y1 17.3MB | Y2 17.3MB  -> total 60.3 MB. XC aliases X.
  char* w = (char*)d_ws;
  int*  flag = (int*)w;
  bf16* A  = (bf16*)(w + 16);
  bf16* X  = A + (size_t)Nn * Nn;
  bf16* Y1 = X + (size_t)Nn * BC;
  bf16* Y2 = Y1 + (size_t)Nn * BC;

  detect_kernel<<<1, 64, 0, stream>>>(E, flag);
  support_kernel<<<Nn, 256, 0, stream>>>(E, mask, normalize, flag, A);
  build_x_kernel<<<(Nn * BC + 255) / 256, 256, 0, stream>>>(x, state, flag, X);

  dim3 g(BC / 128, Nn / 128);  // (33, 16)
  gemm_bf16<<<g, 256, 0, stream>>>(A, X,  Y1, Nn, BC, Nn);   // Y1 = A@X
  gemm_bf16<<<g, 256, 0, stream>>>(A, Y1, Y2, Nn, BC, Nn);   // Y2 = A@Y1

  gate_kernel<<<Nn, 256, 0, stream>>>(X, Y1, Y2, E, gW, gb, x, state, flag, d_out);

  gemm_bf16<<<g, 256, 0, stream>>>(A, X,  Y1, Nn, BC, Nn);   // Y1 = A@XC (X holds candidate)
  gemm_bf16<<<g, 256, 0, stream>>>(A, Y1, Y2, Nn, BC, Nn);   // Y2 = A@Y1

  update_kernel<<<Nn, 256, 0, stream>>>(X, Y1, Y2, E, uW, ub, state, flag, d_out);
}

// Round 4
// 1029.371 us; speedup vs baseline: 3.6583x; 3.6583x over previous
//
#include <hip/hip_runtime.h>
#include <hip/hip_bf16.h>
#include <cstdint>
#include <cmath>

typedef unsigned short u16;
typedef __attribute__((ext_vector_type(8))) short bf16x8;
typedef __attribute__((ext_vector_type(4))) float f32x4;

__device__ __forceinline__ float bu2f(u16 u) { return __uint_as_float((unsigned)u << 16); }
__device__ __forceinline__ u16 f2bu(float v) {
  union { __hip_bfloat16 h; u16 u; } c; c.h = __float2bfloat16(v); return c.u;
}
// dtype-flagged scalar load: f32 ? fp32 : bf16
__device__ __forceinline__ float ldf(const void* p, size_t i, int f32) {
  return f32 ? ((const float*)p)[i] : bu2f(((const u16*)p)[i]);
}
// async 16B global->LDS (lane l lands at lds + l*16)
__device__ __forceinline__ void gll16(const u16* g, u16* lds) {
  __builtin_amdgcn_global_load_lds((const __attribute__((address_space(1))) unsigned*)g,
                                   (__attribute__((address_space(3))) unsigned*)lds, 16, 0, 0);
}

constexpr int Nn = 2048, Bb = 64, Dd = 16, Cc = 66, Hh = 64, BC = 4224;

// ---------------------------------------------------------------------------
__global__ void detect_kernel(const void* __restrict__ E, int* __restrict__ flag) {
  if (threadIdx.x == 0) {
    const unsigned* p = (const unsigned*)E;
    int hits = 0;
    for (int i = 0; i < 64; i++) {
      unsigned ex = (p[i] >> 7) & 0xFF;
      hits += (ex >= 100 && ex <= 140) ? 1 : 0;
    }
    *flag = (hits < 32) ? 1 : 0;   // 1 -> inputs are fp32
  }
}

// ---------------------------------------------------------------------------
// A[n,m] = softmax_m(relu(E[n]·E[m])) * mask  (+ optional re-softmax), bf16 out
// ---------------------------------------------------------------------------
__global__ __launch_bounds__(256) void support_kernel(
    const void* __restrict__ E, const void* __restrict__ mask,
    const int* __restrict__ normalize, const int* __restrict__ flag,
    u16* __restrict__ A) {
  __shared__ float row[Nn];
  __shared__ float red[256];
  __shared__ float en[Dd];
  int f = *flag;
  int n = blockIdx.x, t = threadIdx.x;
  if (t < Dd) en[t] = ldf(E, (size_t)n * Dd + t, f);
  __syncthreads();

  float lmax = -1e30f;
  for (int m = t; m < Nn; m += 256) {
    float s = 0.f;
#pragma unroll
    for (int d = 0; d < Dd; d++) s += en[d] * ldf(E, (size_t)m * Dd + d, f);
    s = fmaxf(s, 0.f);
    row[m] = s; lmax = fmaxf(lmax, s);
  }
  red[t] = lmax; __syncthreads();
  for (int w = 128; w > 0; w >>= 1) { if (t < w) red[t] = fmaxf(red[t], red[t + w]); __syncthreads(); }
  float mx = red[0]; __syncthreads();
  float lsum = 0.f;
  for (int m = t; m < Nn; m += 256) { float e = expf(row[m] - mx); row[m] = e; lsum += e; }
  red[t] = lsum; __syncthreads();
  for (int w = 128; w > 0; w >>= 1) { if (t < w) red[t] += red[t + w]; __syncthreads(); }
  float inv = 1.f / red[0]; __syncthreads();
  for (int m = t; m < Nn; m += 256)
    row[m] = row[m] * inv * ldf(mask, (size_t)n * Nn + m, f);

  if (*normalize != 0) {
    __syncthreads();
    lmax = -1e30f;
    for (int m = t; m < Nn; m += 256) lmax = fmaxf(lmax, row[m]);
    red[t] = lmax; __syncthreads();
    for (int w = 128; w > 0; w >>= 1) { if (t < w) red[t] = fmaxf(red[t], red[t + w]); __syncthreads(); }
    mx = red[0]; __syncthreads();
    lsum = 0.f;
    for (int m = t; m < Nn; m += 256) { float e = expf(row[m] - mx); row[m] = e; lsum += e; }
    red[t] = lsum; __syncthreads();
    for (int w = 128; w > 0; w >>= 1) { if (t < w) red[t] += red[t + w]; __syncthreads(); }
    inv = 1.f / red[0]; __syncthreads();
    for (int m = t; m < Nn; m += 256) row[m] *= inv;
  }
  __syncthreads();
  for (int m = t; m < Nn; m += 256) A[(size_t)n * Nn + m] = f2bu(row[m]);
}

// ---------------------------------------------------------------------------
// Xt[j][m] = bf16(concat(x,state)[b,m,c]),  j = b*66+c.  Tiled: coalesced both ways.
// ---------------------------------------------------------------------------
__global__ __launch_bounds__(256) void build_xt_kernel(
    const void* __restrict__ x, const void* __restrict__ state,
    const int* __restrict__ flag, u16* __restrict__ Xt) {
  __shared__ float sx[66][65];
  int f = *flag;
  int m0 = blockIdx.x * 64, b = blockIdx.y;
  int t = threadIdx.x;
  {
    int cl = t & 63, mg = t >> 6;
    for (int cb = 0; cb < 2; cb++) {
      int c = cb * 64 + cl;
      if (c < 66)
        for (int m = mg; m < 64; m += 4)
          sx[c][m] = (c < 2) ? ldf(x, ((size_t)b * Nn + m0 + m) * 2 + c, f)
                             : ldf(state, ((size_t)b * Nn + m0 + m) * Hh + (c - 2), f);
    }
  }
  __syncthreads();
  for (int cb = 0; cb < 2; cb++) {
    int ch = t >> 2;
    int c = cb * 64 + ch;
    if (c < 66 && (cb == 0 || ch < 2)) {
      int mq = t & 3;
      __align__(16) u16 tmp[16];
#pragma unroll
      for (int i = 0; i < 16; i++) tmp[i] = f2bu(sx[c][mq * 16 + i]);
      *(uint4*)&Xt[(size_t)(b * 66 + c) * 2048 + m0 + mq * 16] = *(uint4*)&tmp[0];
      *(uint4*)&Xt[(size_t)(b * 66 + c) * 2048 + m0 + mq * 16 + 8] = *(uint4*)&tmp[8];
    }
  }
}

// ---------------------------------------------------------------------------
// MFMA GEMM: C[m][j] = sum_k A[m][k] * Bt[j][k].  M=2048, J=4224, K=2048.
// 128x128x32 tiles, global_load_lds w/ XOR chunk swizzle, 4x4 mfma tiles/wave.
// Writes C node-major [2048][4224]; optionally Ct [4224][2048].
// ---------------------------------------------------------------------------
__global__ __launch_bounds__(256) void gemm_bt(
    const u16* __restrict__ A, const u16* __restrict__ Bt,
    u16* __restrict__ C, u16* __restrict__ Ct) {
  __shared__ __align__(16) u16 As[128 * 32];
  __shared__ __align__(16) u16 Bs[128 * 32];
  const int t = threadIdx.x;
  const int wave = t >> 6, lane = t & 63;
  const int bm = blockIdx.y * 128, bj = blockIdx.x * 128;
  const int wm = (wave >> 1) * 64, wj = (wave & 1) * 64;
  const int lr = lane >> 2;              // row within 16-row staging group
  const int gc = (lane & 3) ^ (lr & 3);  // swizzled source chunk
  const int ln = lane & 15, q = lane >> 4;
  const int sw = ((q ^ (ln & 3)) << 3);  // swizzled frag-read elem offset

  f32x4 acc[4][4];
#pragma unroll
  for (int i = 0; i < 4; i++)
#pragma unroll
    for (int j = 0; j < 4; j++) acc[i][j] = (f32x4){0.f, 0.f, 0.f, 0.f};

  for (int k0 = 0; k0 < 2048; k0 += 32) {
#pragma unroll
    for (int p = 0; p < 2; p++) {
      int rb = wave * 32 + p * 16;
      gll16(&A[(size_t)(bm + rb + lr) * 2048 + k0 + gc * 8], &As[rb * 32]);
      gll16(&Bt[(size_t)(bj + rb + lr) * 2048 + k0 + gc * 8], &Bs[rb * 32]);
    }
    __syncthreads();
    bf16x8 af[4], bfr[4];
#pragma unroll
    for (int i = 0; i < 4; i++) af[i] = *(const bf16x8*)&As[(wm + i * 16 + ln) * 32 + sw];
#pragma unroll
    for (int j = 0; j < 4; j++) bfr[j] = *(const bf16x8*)&Bs[(wj + j * 16 + ln) * 32 + sw];
#pragma unroll
    for (int i = 0; i < 4; i++)
#pragma unroll
      for (int j = 0; j < 4; j++)
        acc[i][j] = __builtin_amdgcn_mfma_f32_16x16x32_bf16(af[i], bfr[j], acc[i][j], 0, 0, 0);
    __syncthreads();
  }
#pragma unroll
  for (int i = 0; i < 4; i++) {
    int mg = bm + wm + i * 16 + q * 4;
#pragma unroll
    for (int j = 0; j < 4; j++) {
      int jg = bj + wj + j * 16 + ln;
      f32x4 v = acc[i][j];
      u16 h0 = f2bu(v[0]), h1 = f2bu(v[1]), h2 = f2bu(v[2]), h3 = f2bu(v[3]);
      if (Ct) {
        uint2 pk = make_uint2((unsigned)h0 | ((unsigned)h1 << 16),
                              (unsigned)h2 | ((unsigned)h3 << 16));
        *(uint2*)&Ct[(size_t)jg * 2048 + mg] = pk;
      }
      C[(size_t)(mg + 0) * 4224 + jg] = h0;
      C[(size_t)(mg + 1) * 4224 + jg] = h1;
      C[(size_t)(mg + 2) * 4224 + jg] = h2;
      C[(size_t)(mg + 3) * 4224 + jg] = h3;
    }
  }
}

// ---------------------------------------------------------------------------
// Tiled transpose: S [2048][4224] -> D [4224][2048]
// ---------------------------------------------------------------------------
__global__ __launch_bounds__(256) void transpose_kernel(
    const u16* __restrict__ S, u16* __restrict__ D) {
  __shared__ u16 sm[64][70];
  int j0 = blockIdx.x * 64, m0 = blockIdx.y * 64;
  int t = threadIdx.x;
  {
    int c = t & 63, r0 = t >> 6;
    for (int r = r0; r < 64; r += 4)
      sm[r][c] = S[(size_t)(m0 + r) * 4224 + j0 + c];
  }
  __syncthreads();
  {
    int jl = t >> 2, mq = t & 3;
    __align__(16) u16 tmp[16];
#pragma unroll
    for (int i = 0; i < 16; i++) tmp[i] = sm[mq * 16 + i][jl];
    *(uint4*)&D[(size_t)(j0 + jl) * 2048 + m0 + mq * 16] = *(uint4*)&tmp[0];
    *(uint4*)&D[(size_t)(j0 + jl) * 2048 + m0 + mq * 16 + 8] = *(uint4*)&tmp[8];
  }
}

// ---------------------------------------------------------------------------
// Gate: one block per node. Chunked W-fold (fp32, once per block) + fp32 einsum.
// Writes r -> d_out, candidate -> XC (bf16 [2048][4224]).
// ---------------------------------------------------------------------------
__global__ __launch_bounds__(256) void gate_kernel(
    const u16* __restrict__ Y1, const u16* __restrict__ Y2,
    const void* __restrict__ x, const void* __restrict__ state,
    const void* __restrict__ E, const void* __restrict__ W, const void* __restrict__ bp,
    const int* __restrict__ flag, void* Rout, u16* __restrict__ XC) {
  __shared__ float xg[64][208];
  __shared__ float wnc[128][20];
  __shared__ float en_s[16];
  const int f = *flag;
  const int n = blockIdx.x, t = threadIdx.x;
  if (t < 16) en_s[t] = ldf(E, (size_t)n * 16 + t, f);

  for (int j = t; j < 64 * 66; j += 256) {
    int b = j / 66, c = j - b * 66;
    float v0 = (c < 2) ? ldf(x, ((size_t)b * Nn + n) * 2 + c, f)
                       : ldf(state, ((size_t)b * Nn + n) * Hh + (c - 2), f);
    xg[b][c] = v0;
    xg[b][66 + c] = bu2f(Y1[(size_t)n * BC + j]);
    xg[b][132 + c] = 2.f * bu2f(Y2[(size_t)n * BC + j]) - v0;
  }
  for (int j = t; j < 64 * 10; j += 256) xg[j / 10][198 + (j % 10)] = 0.f;

  const int o8 = t & 15, kl = t >> 4;   // fold mapping
  const int o = t & 127, bg = t >> 7;   // einsum mapping
  float acc[32];
#pragma unroll
  for (int i = 0; i < 32; i++) acc[i] = 0.f;

  for (int c0 = 0; c0 < 208; c0 += 16) {
    __syncthreads();
    {
      int ki = c0 + kl;
      float a8[8];
#pragma unroll
      for (int j = 0; j < 8; j++) a8[j] = 0.f;
      if (ki < 198) {
        if (f) {
          const float* Wf = (const float*)W;
#pragma unroll
          for (int d = 0; d < 16; d++) {
            float4 w0 = *(const float4*)&Wf[(size_t)(d * 198 + ki) * 128 + o8 * 8];
            float4 w1 = *(const float4*)&Wf[(size_t)(d * 198 + ki) * 128 + o8 * 8 + 4];
            float e = en_s[d];
            a8[0] = fmaf(e, w0.x, a8[0]); a8[1] = fmaf(e, w0.y, a8[1]);
            a8[2] = fmaf(e, w0.z, a8[2]); a8[3] = fmaf(e, w0.w, a8[3]);
            a8[4] = fmaf(e, w1.x, a8[4]); a8[5] = fmaf(e, w1.y, a8[5]);
            a8[6] = fmaf(e, w1.z, a8[6]); a8[7] = fmaf(e, w1.w, a8[7]);
          }
        } else {
          const u16* Wb = (const u16*)W;
#pragma unroll
          for (int d = 0; d < 16; d++) {
            const u16* p = &Wb[(size_t)(d * 198 + ki) * 128 + o8 * 8];
            float e = en_s[d];
#pragma unroll
            for (int j = 0; j < 8; j++) a8[j] = fmaf(e, bu2f(p[j]), a8[j]);
          }
        }
      }
#pragma unroll
      for (int j = 0; j < 8; j++) wnc[o8 * 8 + j][kl] = a8[j];
    }
    __syncthreads();
#pragma unroll 1
    for (int kq = 0; kq < 4; kq++) {
      float4 wv = *(const float4*)&wnc[o][kq * 4];
#pragma unroll
      for (int bi = 0; bi < 32; bi++) {
        float4 xv = *(const float4*)&xg[bg * 32 + bi][c0 + kq * 4];
        acc[bi] = fmaf(wv.x, xv.x, acc[bi]);
        acc[bi] = fmaf(wv.y, xv.y, acc[bi]);
        acc[bi] = fmaf(wv.z, xv.z, acc[bi]);
        acc[bi] = fmaf(wv.w, xv.w, acc[bi]);
      }
    }
  }

  float bias = 0.f;
#pragma unroll
  for (int d = 0; d < 16; d++) bias += en_s[d] * ldf(bp, (size_t)d * 128 + o, f);
#pragma unroll
  for (int bi = 0; bi < 32; bi++) {
    int b = bg * 32 + bi;
    float v = 1.f / (1.f + expf(-(acc[bi] + bias)));
    if (o < 64) {   // z -> candidate = z * state
      float s = ldf(state, ((size_t)b * Nn + n) * Hh + o, f);
      XC[(size_t)n * BC + b * 66 + 2 + o] = f2bu(v * s);
    } else {        // r -> parked in d_out
      size_t idx = ((size_t)b * Nn + n) * Hh + (o - 64);
      if (f) ((float*)Rout)[idx] = v; else ((u16*)Rout)[idx] = f2bu(v);
    }
  }
  if (t < 128) {    // candidate x-part
    int b = t >> 1, c = t & 1;
    XC[(size_t)n * BC + b * 66 + c] = f2bu(ldf(x, ((size_t)b * Nn + n) * 2 + c, f));
  }
}

// ---------------------------------------------------------------------------
// Update: same structure, o-dim 64; out = r*state + (1-r)*tanh(...)
// ---------------------------------------------------------------------------
__global__ __launch_bounds__(256) void update_kernel(
    const u16* __restrict__ XCn, const u16* __restrict__ Y1, const u16* __restrict__ Y2,
    const void* __restrict__ E, const void* __restrict__ W, const void* __restrict__ bp,
    const void* __restrict__ state, const int* __restrict__ flag, void* out) {
  __shared__ float xg[64][208];
  __shared__ float wnc[64][20];
  __shared__ float en_s[16];
  const int f = *flag;
  const int n = blockIdx.x, t = threadIdx.x;
  if (t < 16) en_s[t] = ldf(E, (size_t)n * 16 + t, f);

  for (int j = t; j < 64 * 66; j += 256) {
    int b = j / 66, c = j - b * 66;
    float v0 = bu2f(XCn[(size_t)n * BC + j]);
    xg[b][c] = v0;
    xg[b][66 + c] = bu2f(Y1[(size_t)n * BC + j]);
    xg[b][132 + c] = 2.f * bu2f(Y2[(size_t)n * BC + j]) - v0;
  }
  for (int j = t; j < 64 * 10; j += 256) xg[j / 10][198 + (j % 10)] = 0.f;

  const int o4 = t & 15, kl = t >> 4;   // fold mapping (4 o's each)
  const int o = t & 63, bg = t >> 6;    // einsum mapping
  float acc[16];
#pragma unroll
  for (int i = 0; i < 16; i++) acc[i] = 0.f;

  for (int c0 = 0; c0 < 208; c0 += 16) {
    __syncthreads();
    {
      int ki = c0 + kl;
      float a4[4];
#pragma unroll
      for (int j = 0; j < 4; j++) a4[j] = 0.f;
      if (ki < 198) {
        if (f) {
          const float* Wf = (const float*)W;
#pragma unroll
          for (int d = 0; d < 16; d++) {
            float4 w0 = *(const float4*)&Wf[(size_t)(d * 198 + ki) * 64 + o4 * 4];
            float e = en_s[d];
            a4[0] = fmaf(e, w0.x, a4[0]); a4[1] = fmaf(e, w0.y, a4[1]);
            a4[2] = fmaf(e, w0.z, a4[2]); a4[3] = fmaf(e, w0.w, a4[3]);
          }
        } else {
          const u16* Wb = (const u16*)W;
#pragma unroll
          for (int d = 0; d < 16; d++) {
            const u16* p = &Wb[(size_t)(d * 198 + ki) * 64 + o4 * 4];
            float e = en_s[d];
#pragma unroll
            for (int j = 0; j < 4; j++) a4[j] = fmaf(e, bu2f(p[j]), a4[j]);
          }
        }
      }
#pragma unroll
      for (int j = 0; j < 4; j++) wnc[o4 * 4 + j][kl] = a4[j];
    }
    __syncthreads();
#pragma unroll 1
    for (int kq = 0; kq < 4; kq++) {
      float4 wv = *(const float4*)&wnc[o][kq * 4];
#pragma unroll
      for (int bi = 0; bi < 16; bi++) {
        float4 xv = *(const float4*)&xg[bg * 16 + bi][c0 + kq * 4];
        acc[bi] = fmaf(wv.x, xv.x, acc[bi]);
        acc[bi] = fmaf(wv.y, xv.y, acc[bi]);
        acc[bi] = fmaf(wv.z, xv.z, acc[bi]);
        acc[bi] = fmaf(wv.w, xv.w, acc[bi]);
      }
    }
  }

  float bias = 0.f;
#pragma unroll
  for (int d = 0; d < 16; d++) bias += en_s[d] * ldf(bp, (size_t)d * 64 + o, f);
#pragma unroll
  for (int bi = 0; bi < 16; bi++) {
    int b = bg * 16 + bi;
    size_t idx = ((size_t)b * Nn + n) * Hh + o;
    float hc = tanhf(acc[bi] + bias);
    float r = f ? ((const float*)out)[idx] : bu2f(((const u16*)out)[idx]);
    float s = ldf(state, idx, f);
    float v = r * s + (1.f - r) * hc;
    if (f) ((float*)out)[idx] = v; else ((u16*)out)[idx] = f2bu(v);
  }
}

// ---------------------------------------------------------------------------
extern "C" void kernel_launch(void* const* d_in, const int* in_sizes, int n_in,
                              void* d_out, int out_size, void* d_ws, size_t ws_size,
                              hipStream_t stream) {
  const void* x     = d_in[0];
  const void* state = d_in[1];
  const void* E     = d_in[2];
  const void* mask  = d_in[3];
  const void* gW    = d_in[4];
  const void* gb    = d_in[5];
  const void* uW    = d_in[6];
  const void* ub    = d_in[7];
  const int* normalize = (const int*)d_in[8];

  // ws layout (77.6 MB): flag | A[2048][2048] | Xt/XC | Y1t | Y1 | Q(Y2/XCt/Y2')
  char* w = (char*)d_ws;
  int* flag = (int*)w;
  u16* A   = (u16*)(w + 64);
  u16* Xt  = A   + (size_t)Nn * Nn;    // also holds XC (candidate, node-major) later
  u16* Y1t = Xt  + (size_t)Nn * BC;
  u16* Y1  = Y1t + (size_t)Nn * BC;
  u16* Q   = Y1  + (size_t)Nn * BC;

  detect_kernel<<<1, 64, 0, stream>>>(E, flag);
  support_kernel<<<Nn, 256, 0, stream>>>(E, mask, normalize, flag, A);
  build_xt_kernel<<<dim3(32, 64), 256, 0, stream>>>(x, state, flag, Xt);

  dim3 g(33, 16);
  gemm_bt<<<g, 256, 0, stream>>>(A, Xt, Y1, Y1t);        // Y1 = A@X   (+Y1t)
  gemm_bt<<<g, 256, 0, stream>>>(A, Y1t, Q, nullptr);    // Y2 = A@Y1  (node-major)

  gate_kernel<<<Nn, 256, 0, stream>>>(Y1, Q, x, state, E, gW, gb, flag, d_out, Xt);

  transpose_kernel<<<dim3(66, 32), 256, 0, stream>>>(Xt, Q);   // XCt in Q
  gemm_bt<<<g, 256, 0, stream>>>(A, Q, Y1, Y1t);         // Y1 = A@XC  (+Y1t)
  gemm_bt<<<g, 256, 0, stream>>>(A, Y1t, Q, nullptr);    // Y2' = A@Y1

  update_kernel<<<Nn, 256, 0, stream>>>(Xt, Y1, Q, E, uW, ub, state, flag, d_out);
}

// Round 5
// 719.161 us; speedup vs baseline: 5.2363x; 1.4313x over previous
//
#include <hip/hip_runtime.h>
#include <hip/hip_bf16.h>
#include <cstdint>
#include <cmath>

typedef unsigned short u16;
typedef __attribute__((ext_vector_type(8))) short bf16x8;
typedef __attribute__((ext_vector_type(4))) float f32x4;

__device__ __forceinline__ float bu2f(u16 u) { return __uint_as_float((unsigned)u << 16); }
__device__ __forceinline__ u16 f2bu(float v) {
  union { __hip_bfloat16 h; u16 u; } c; c.h = __float2bfloat16(v); return c.u;
}
__device__ __forceinline__ float ldf(const void* p, size_t i, int f32) {
  return f32 ? ((const float*)p)[i] : bu2f(((const u16*)p)[i]);
}
__device__ __forceinline__ void gll16(const u16* g, u16* lds) {
  __builtin_amdgcn_global_load_lds((const __attribute__((address_space(1))) unsigned*)g,
                                   (__attribute__((address_space(3))) unsigned*)lds, 16, 0, 0);
}

constexpr int Nn = 2048, Bb = 64, Dd = 16, Cc = 66, Hh = 64, BC = 4224;
constexpr int KP = 224;   // padded ki (198 -> 224 = 7*32)

// ---------------------------------------------------------------------------
__global__ void detect_kernel(const void* __restrict__ E, int* __restrict__ flag) {
  if (threadIdx.x == 0) {
    const unsigned* p = (const unsigned*)E;
    int hits = 0;
    for (int i = 0; i < 64; i++) {
      unsigned ex = (p[i] >> 7) & 0xFF;
      hits += (ex >= 100 && ex <= 140) ? 1 : 0;
    }
    *flag = (hits < 32) ? 1 : 0;   // 1 -> inputs are fp32
  }
}

// ---------------------------------------------------------------------------
__global__ __launch_bounds__(256) void support_kernel(
    const void* __restrict__ E, const void* __restrict__ mask,
    const int* __restrict__ normalize, const int* __restrict__ flag,
    u16* __restrict__ A) {
  __shared__ float row[Nn];
  __shared__ float red[256];
  __shared__ float en[Dd];
  int f = *flag;
  int n = blockIdx.x, t = threadIdx.x;
  if (t < Dd) en[t] = ldf(E, (size_t)n * Dd + t, f);
  __syncthreads();

  float lmax = -1e30f;
  for (int m = t; m < Nn; m += 256) {
    float s = 0.f;
#pragma unroll
    for (int d = 0; d < Dd; d++) s += en[d] * ldf(E, (size_t)m * Dd + d, f);
    s = fmaxf(s, 0.f);
    row[m] = s; lmax = fmaxf(lmax, s);
  }
  red[t] = lmax; __syncthreads();
  for (int w = 128; w > 0; w >>= 1) { if (t < w) red[t] = fmaxf(red[t], red[t + w]); __syncthreads(); }
  float mx = red[0]; __syncthreads();
  float lsum = 0.f;
  for (int m = t; m < Nn; m += 256) { float e = expf(row[m] - mx); row[m] = e; lsum += e; }
  red[t] = lsum; __syncthreads();
  for (int w = 128; w > 0; w >>= 1) { if (t < w) red[t] += red[t + w]; __syncthreads(); }
  float inv = 1.f / red[0]; __syncthreads();
  for (int m = t; m < Nn; m += 256)
    row[m] = row[m] * inv * ldf(mask, (size_t)n * Nn + m, f);

  if (*normalize != 0) {
    __syncthreads();
    lmax = -1e30f;
    for (int m = t; m < Nn; m += 256) lmax = fmaxf(lmax, row[m]);
    red[t] = lmax; __syncthreads();
    for (int w = 128; w > 0; w >>= 1) { if (t < w) red[t] = fmaxf(red[t], red[t + w]); __syncthreads(); }
    mx = red[0]; __syncthreads();
    lsum = 0.f;
    for (int m = t; m < Nn; m += 256) { float e = expf(row[m] - mx); row[m] = e; lsum += e; }
    red[t] = lsum; __syncthreads();
    for (int w = 128; w > 0; w >>= 1) { if (t < w) red[t] += red[t + w]; __syncthreads(); }
    inv = 1.f / red[0]; __syncthreads();
    for (int m = t; m < Nn; m += 256) row[m] *= inv;
  }
  __syncthreads();
  for (int m = t; m < Nn; m += 256) A[(size_t)n * Nn + m] = f2bu(row[m]);
}

// ---------------------------------------------------------------------------
__global__ __launch_bounds__(256) void build_xt_kernel(
    const void* __restrict__ x, const void* __restrict__ state,
    const int* __restrict__ flag, u16* __restrict__ Xt) {
  __shared__ float sx[66][65];
  int f = *flag;
  int m0 = blockIdx.x * 64, b = blockIdx.y;
  int t = threadIdx.x;
  {
    int cl = t & 63, mg = t >> 6;
    for (int cb = 0; cb < 2; cb++) {
      int c = cb * 64 + cl;
      if (c < 66)
        for (int m = mg; m < 64; m += 4)
          sx[c][m] = (c < 2) ? ldf(x, ((size_t)b * Nn + m0 + m) * 2 + c, f)
                             : ldf(state, ((size_t)b * Nn + m0 + m) * Hh + (c - 2), f);
    }
  }
  __syncthreads();
  for (int cb = 0; cb < 2; cb++) {
    int ch = t >> 2;
    int c = cb * 64 + ch;
    if (c < 66 && (cb == 0 || ch < 2)) {
      int mq = t & 3;
      __align__(16) u16 tmp[16];
#pragma unroll
      for (int i = 0; i < 16; i++) tmp[i] = f2bu(sx[c][mq * 16 + i]);
      *(uint4*)&Xt[(size_t)(b * 66 + c) * 2048 + m0 + mq * 16] = *(uint4*)&tmp[0];
      *(uint4*)&Xt[(size_t)(b * 66 + c) * 2048 + m0 + mq * 16 + 8] = *(uint4*)&tmp[8];
    }
  }
}

// ---------------------------------------------------------------------------
__global__ __launch_bounds__(256) void gemm_bt(
    const u16* __restrict__ A, const u16* __restrict__ Bt,
    u16* __restrict__ C, u16* __restrict__ Ct) {
  __shared__ __align__(16) u16 As[128 * 32];
  __shared__ __align__(16) u16 Bs[128 * 32];
  const int t = threadIdx.x;
  const int wave = t >> 6, lane = t & 63;
  const int bm = blockIdx.y * 128, bj = blockIdx.x * 128;
  const int wm = (wave >> 1) * 64, wj = (wave & 1) * 64;
  const int lr = lane >> 2;
  const int gc = (lane & 3) ^ (lr & 3);
  const int ln = lane & 15, q = lane >> 4;
  const int sw = ((q ^ (ln & 3)) << 3);

  f32x4 acc[4][4];
#pragma unroll
  for (int i = 0; i < 4; i++)
#pragma unroll
    for (int j = 0; j < 4; j++) acc[i][j] = (f32x4){0.f, 0.f, 0.f, 0.f};

  for (int k0 = 0; k0 < 2048; k0 += 32) {
#pragma unroll
    for (int p = 0; p < 2; p++) {
      int rb = wave * 32 + p * 16;
      gll16(&A[(size_t)(bm + rb + lr) * 2048 + k0 + gc * 8], &As[rb * 32]);
      gll16(&Bt[(size_t)(bj + rb + lr) * 2048 + k0 + gc * 8], &Bs[rb * 32]);
    }
    __syncthreads();
    bf16x8 af[4], bfr[4];
#pragma unroll
    for (int i = 0; i < 4; i++) af[i] = *(const bf16x8*)&As[(wm + i * 16 + ln) * 32 + sw];
#pragma unroll
    for (int j = 0; j < 4; j++) bfr[j] = *(const bf16x8*)&Bs[(wj + j * 16 + ln) * 32 + sw];
#pragma unroll
    for (int i = 0; i < 4; i++)
#pragma unroll
      for (int j = 0; j < 4; j++)
        acc[i][j] = __builtin_amdgcn_mfma_f32_16x16x32_bf16(af[i], bfr[j], acc[i][j], 0, 0, 0);
    __syncthreads();
  }
#pragma unroll
  for (int i = 0; i < 4; i++) {
    int mg = bm + wm + i * 16 + q * 4;
#pragma unroll
    for (int j = 0; j < 4; j++) {
      int jg = bj + wj + j * 16 + ln;
      f32x4 v = acc[i][j];
      u16 h0 = f2bu(v[0]), h1 = f2bu(v[1]), h2 = f2bu(v[2]), h3 = f2bu(v[3]);
      if (Ct) {
        uint2 pk = make_uint2((unsigned)h0 | ((unsigned)h1 << 16),
                              (unsigned)h2 | ((unsigned)h3 << 16));
        *(uint2*)&Ct[(size_t)jg * 2048 + mg] = pk;
      }
      C[(size_t)(mg + 0) * 4224 + jg] = h0;
      C[(size_t)(mg + 1) * 4224 + jg] = h1;
      C[(size_t)(mg + 2) * 4224 + jg] = h2;
      C[(size_t)(mg + 3) * 4224 + jg] = h3;
    }
  }
}

// ---------------------------------------------------------------------------
__global__ __launch_bounds__(256) void transpose_kernel(
    const u16* __restrict__ S, u16* __restrict__ D) {
  __shared__ u16 sm[64][70];
  int j0 = blockIdx.x * 64, m0 = blockIdx.y * 64;
  int t = threadIdx.x;
  {
    int c = t & 63, r0 = t >> 6;
    for (int r = r0; r < 64; r += 4)
      sm[r][c] = S[(size_t)(m0 + r) * 4224 + j0 + c];
  }
  __syncthreads();
  {
    int jl = t >> 2, mq = t & 3;
    __align__(16) u16 tmp[16];
#pragma unroll
    for (int i = 0; i < 16; i++) tmp[i] = sm[mq * 16 + i][jl];
    *(uint4*)&D[(size_t)(j0 + jl) * 2048 + m0 + mq * 16] = *(uint4*)&tmp[0];
    *(uint4*)&D[(size_t)(j0 + jl) * 2048 + m0 + mq * 16 + 8] = *(uint4*)&tmp[8];
  }
}

// ---------------------------------------------------------------------------
// Fold: Wnt[n_rel][o][KP] (bf16) = sum_d E[n,d] * W[d][ki][o], ki padded ->0.
// Block: 64-node tile x 8-ki slab; W slab held in registers, reused over nodes.
// ---------------------------------------------------------------------------
__global__ __launch_bounds__(256) void fold_kernel(
    const void* __restrict__ E, const void* __restrict__ W,
    u16* __restrict__ Wnt, const int* __restrict__ flag, int n0, int O) {
  __shared__ float Es[64][16];
  const int f = *flag;
  const int t = threadIdx.x;
  const int nb = n0 + blockIdx.x * 64;
  const int ki0 = blockIdx.y * 8;
  for (int j = t; j < 1024; j += 256)
    Es[j >> 4][j & 15] = ldf(E, (size_t)(nb + (j >> 4)) * 16 + (j & 15), f);

  const int o = t & (O - 1);
  const int tpn = 256 / O;         // threads sharing a node range
  const int nh = t / O;            // which node sub-range
  const int NPT = 64 / tpn;        // nodes per thread

  float wv[128];
  if (f) {
    const float* Wf = (const float*)W;
#pragma unroll
    for (int d = 0; d < 16; d++)
#pragma unroll
      for (int i = 0; i < 8; i++) {
        int ki = ki0 + i;
        wv[d * 8 + i] = (ki < 198) ? Wf[((size_t)d * 198 + ki) * O + o] : 0.f;
      }
  } else {
    const u16* Wb = (const u16*)W;
#pragma unroll
    for (int d = 0; d < 16; d++)
#pragma unroll
      for (int i = 0; i < 8; i++) {
        int ki = ki0 + i;
        wv[d * 8 + i] = (ki < 198) ? bu2f(Wb[((size_t)d * 198 + ki) * O + o]) : 0.f;
      }
  }
  __syncthreads();

  for (int r = 0; r < NPT; r++) {
    int nl = nh * NPT + r;
    float en[16];
#pragma unroll
    for (int d = 0; d < 16; d++) en[d] = Es[nl][d];
    float a8[8];
#pragma unroll
    for (int i = 0; i < 8; i++) a8[i] = 0.f;
#pragma unroll
    for (int d = 0; d < 16; d++)
#pragma unroll
      for (int i = 0; i < 8; i++) a8[i] = fmaf(en[d], wv[d * 8 + i], a8[i]);
    unsigned pw[4];
#pragma unroll
    for (int i = 0; i < 4; i++)
      pw[i] = (unsigned)f2bu(a8[2 * i]) | ((unsigned)f2bu(a8[2 * i + 1]) << 16);
    *(uint4*)&Wnt[((size_t)(blockIdx.x * 64 + nl) * O + o) * KP + ki0] =
        make_uint4(pw[0], pw[1], pw[2], pw[3]);
  }
}

// ---------------------------------------------------------------------------
// MFMA per-node einsum, gate (O=128): out = sigmoid(xg @ Wn + b); z->XC, r->Rout
// ---------------------------------------------------------------------------
__global__ __launch_bounds__(256) void avw_gate(
    const u16* __restrict__ Y1, const u16* __restrict__ Y2,
    const void* __restrict__ x, const void* __restrict__ state,
    const void* __restrict__ E, const u16* __restrict__ Wnt,
    const void* __restrict__ bp, const int* __restrict__ flag,
    void* Rout, u16* __restrict__ XC, int n0) {
  __shared__ unsigned xg32[64][116];   // bf16 pairs, row = b, 232 elems/row
  __shared__ float en_s[16];
  const int f = *flag;
  const int bx = blockIdx.x;
  const int n = n0 + bx;
  const int t = threadIdx.x;
  if (t < 16) en_s[t] = ldf(E, (size_t)n * 16 + t, f);

  const unsigned* Y1u = (const unsigned*)(Y1 + (size_t)n * BC);
  const unsigned* Y2u = (const unsigned*)(Y2 + (size_t)n * BC);
  for (int j = t; j < 64 * 33; j += 256) {
    int b = j / 33, cp = j - b * 33, c = cp * 2;
    float x0, x1;
    if (cp == 0) {
      x0 = ldf(x, ((size_t)b * Nn + n) * 2 + 0, f);
      x1 = ldf(x, ((size_t)b * Nn + n) * 2 + 1, f);
    } else {
      x0 = ldf(state, ((size_t)b * Nn + n) * Hh + (c - 2), f);
      x1 = ldf(state, ((size_t)b * Nn + n) * Hh + (c - 1), f);
    }
    unsigned y1 = Y1u[b * 33 + cp];
    unsigned y2 = Y2u[b * 33 + cp];
    float t20 = 2.f * bu2f((u16)(y2 & 0xffff)) - x0;
    float t21 = 2.f * bu2f((u16)(y2 >> 16)) - x1;
    xg32[b][cp]      = (unsigned)f2bu(x0) | ((unsigned)f2bu(x1) << 16);
    xg32[b][33 + cp] = y1;
    xg32[b][66 + cp] = (unsigned)f2bu(t20) | ((unsigned)f2bu(t21) << 16);
  }
  for (int j = t; j < 64 * 17; j += 256) xg32[j / 17][99 + (j - (j / 17) * 17)] = 0u;
  __syncthreads();

  const int wave = t >> 6, lane = t & 63;
  const int ln = lane & 15, q = lane >> 4;
  f32x4 acc[4][2];
#pragma unroll
  for (int i = 0; i < 4; i++) { acc[i][0] = (f32x4){0,0,0,0}; acc[i][1] = (f32x4){0,0,0,0}; }

  const u16* Wrow = Wnt + (size_t)bx * 128 * KP;
  const u16* xg16 = (const u16*)&xg32[0][0];
  for (int k0 = 0; k0 < KP; k0 += 32) {
    bf16x8 bfr[2];
#pragma unroll
    for (int oi = 0; oi < 2; oi++) {
      int o = (wave * 2 + oi) * 16 + ln;
      bfr[oi] = *(const bf16x8*)&Wrow[(size_t)o * KP + k0 + q * 8];
    }
#pragma unroll
    for (int mt = 0; mt < 4; mt++) {
      bf16x8 af = *(const bf16x8*)&xg16[(mt * 16 + ln) * 232 + k0 + q * 8];
      acc[mt][0] = __builtin_amdgcn_mfma_f32_16x16x32_bf16(af, bfr[0], acc[mt][0], 0, 0, 0);
      acc[mt][1] = __builtin_amdgcn_mfma_f32_16x16x32_bf16(af, bfr[1], acc[mt][1], 0, 0, 0);
    }
  }

  float bias[2];
#pragma unroll
  for (int oi = 0; oi < 2; oi++) {
    int o = (wave * 2 + oi) * 16 + ln;
    float s = 0.f;
#pragma unroll
    for (int d = 0; d < 16; d++) s += en_s[d] * ldf(bp, (size_t)d * 128 + o, f);
    bias[oi] = s;
  }
#pragma unroll
  for (int mt = 0; mt < 4; mt++)
#pragma unroll
    for (int oi = 0; oi < 2; oi++) {
      int o = (wave * 2 + oi) * 16 + ln;
#pragma unroll
      for (int r = 0; r < 4; r++) {
        int b = mt * 16 + q * 4 + r;
        float v = 1.f / (1.f + expf(-(acc[mt][oi][r] + bias[oi])));
        if (o < 64) {
          float s = ldf(state, ((size_t)b * Nn + n) * Hh + o, f);
          XC[(size_t)n * BC + b * 66 + 2 + o] = f2bu(v * s);
        } else {
          size_t idx = ((size_t)b * Nn + n) * Hh + (o - 64);
          if (f) ((float*)Rout)[idx] = v; else ((u16*)Rout)[idx] = f2bu(v);
        }
      }
    }
  if (t < 128) {
    int b = t >> 1, c = t & 1;
    XC[(size_t)n * BC + b * 66 + c] = f2bu(ldf(x, ((size_t)b * Nn + n) * 2 + c, f));
  }
}

// ---------------------------------------------------------------------------
// MFMA per-node einsum, update (O=64): hc=tanh(...); out = r*s + (1-r)*hc
// ---------------------------------------------------------------------------
__global__ __launch_bounds__(256) void avw_update(
    const u16* __restrict__ XCn, const u16* __restrict__ Y1, const u16* __restrict__ Y2,
    const void* __restrict__ E, const u16* __restrict__ Wnt,
    const void* __restrict__ bp, const void* __restrict__ state,
    const int* __restrict__ flag, void* out, int n0) {
  __shared__ unsigned xg32[64][116];
  __shared__ float en_s[16];
  const int f = *flag;
  const int bx = blockIdx.x;
  const int n = n0 + bx;
  const int t = threadIdx.x;
  if (t < 16) en_s[t] = ldf(E, (size_t)n * 16 + t, f);

  const unsigned* XCu = (const unsigned*)(XCn + (size_t)n * BC);
  const unsigned* Y1u = (const unsigned*)(Y1 + (size_t)n * BC);
  const unsigned* Y2u = (const unsigned*)(Y2 + (size_t)n * BC);
  for (int j = t; j < 64 * 33; j += 256) {
    int b = j / 33, cp = j - b * 33;
    unsigned x01 = XCu[b * 33 + cp];
    unsigned y1 = Y1u[b * 33 + cp];
    unsigned y2 = Y2u[b * 33 + cp];
    float x0 = bu2f((u16)(x01 & 0xffff)), x1 = bu2f((u16)(x01 >> 16));
    float t20 = 2.f * bu2f((u16)(y2 & 0xffff)) - x0;
    float t21 = 2.f * bu2f((u16)(y2 >> 16)) - x1;
    xg32[b][cp]      = x01;
    xg32[b][33 + cp] = y1;
    xg32[b][66 + cp] = (unsigned)f2bu(t20) | ((unsigned)f2bu(t21) << 16);
  }
  for (int j = t; j < 64 * 17; j += 256) xg32[j / 17][99 + (j - (j / 17) * 17)] = 0u;
  __syncthreads();

  const int wave = t >> 6, lane = t & 63;
  const int ln = lane & 15, q = lane >> 4;
  f32x4 acc[4];
#pragma unroll
  for (int i = 0; i < 4; i++) acc[i] = (f32x4){0, 0, 0, 0};

  const u16* Wrow = Wnt + (size_t)bx * 64 * KP;
  const u16* xg16 = (const u16*)&xg32[0][0];
  const int o = wave * 16 + ln;
  for (int k0 = 0; k0 < KP; k0 += 32) {
    bf16x8 bfr = *(const bf16x8*)&Wrow[(size_t)o * KP + k0 + q * 8];
#pragma unroll
    for (int mt = 0; mt < 4; mt++) {
      bf16x8 af = *(const bf16x8*)&xg16[(mt * 16 + ln) * 232 + k0 + q * 8];
      acc[mt] = __builtin_amdgcn_mfma_f32_16x16x32_bf16(af, bfr, acc[mt], 0, 0, 0);
    }
  }

  float bias = 0.f;
#pragma unroll
  for (int d = 0; d < 16; d++) bias += en_s[d] * ldf(bp, (size_t)d * 64 + o, f);
#pragma unroll
  for (int mt = 0; mt < 4; mt++)
#pragma unroll
    for (int r = 0; r < 4; r++) {
      int b = mt * 16 + q * 4 + r;
      size_t idx = ((size_t)b * Nn + n) * Hh + o;
      float hc = tanhf(acc[mt][r] + bias);
      float rr = f ? ((const float*)out)[idx] : bu2f(((const u16*)out)[idx]);
      float s = ldf(state, idx, f);
      float v = rr * s + (1.f - rr) * hc;
      if (f) ((float*)out)[idx] = v; else ((u16*)out)[idx] = f2bu(v);
    }
}

// ---------------------------------------------------------------------------
// Fallback (round-4) gate/update for tiny workspaces
// ---------------------------------------------------------------------------
__global__ __launch_bounds__(256) void gate_kernel_fb(
    const u16* __restrict__ Y1, const u16* __restrict__ Y2,
    const void* __restrict__ x, const void* __restrict__ state,
    const void* __restrict__ E, const void* __restrict__ W, const void* __restrict__ bp,
    const int* __restrict__ flag, void* Rout, u16* __restrict__ XC) {
  __shared__ float xg[64][208];
  __shared__ float wnc[128][20];
  __shared__ float en_s[16];
  const int f = *flag;
  const int n = blockIdx.x, t = threadIdx.x;
  if (t < 16) en_s[t] = ldf(E, (size_t)n * 16 + t, f);
  for (int j = t; j < 64 * 66; j += 256) {
    int b = j / 66, c = j - b * 66;
    float v0 = (c < 2) ? ldf(x, ((size_t)b * Nn + n) * 2 + c, f)
                       : ldf(state, ((size_t)b * Nn + n) * Hh + (c - 2), f);
    xg[b][c] = v0;
    xg[b][66 + c] = bu2f(Y1[(size_t)n * BC + j]);
    xg[b][132 + c] = 2.f * bu2f(Y2[(size_t)n * BC + j]) - v0;
  }
  for (int j = t; j < 64 * 10; j += 256) xg[j / 10][198 + (j % 10)] = 0.f;
  const int o8 = t & 15, kl = t >> 4;
  const int o = t & 127, bg = t >> 7;
  float acc[32];
#pragma unroll
  for (int i = 0; i < 32; i++) acc[i] = 0.f;
  for (int c0 = 0; c0 < 208; c0 += 16) {
    __syncthreads();
    {
      int ki = c0 + kl;
      float a8[8];
#pragma unroll
      for (int j = 0; j < 8; j++) a8[j] = 0.f;
      if (ki < 198) {
#pragma unroll
        for (int d = 0; d < 16; d++) {
          float e = en_s[d];
#pragma unroll
          for (int j = 0; j < 8; j++)
            a8[j] = fmaf(e, ldf(W, (size_t)(d * 198 + ki) * 128 + o8 * 8 + j, f), a8[j]);
        }
      }
#pragma unroll
      for (int j = 0; j < 8; j++) wnc[o8 * 8 + j][kl] = a8[j];
    }
    __syncthreads();
#pragma unroll 1
    for (int kq = 0; kq < 4; kq++) {
      float4 wv = *(const float4*)&wnc[o][kq * 4];
#pragma unroll
      for (int bi = 0; bi < 32; bi++) {
        float4 xv = *(const float4*)&xg[bg * 32 + bi][c0 + kq * 4];
        acc[bi] = fmaf(wv.x, xv.x, acc[bi]); acc[bi] = fmaf(wv.y, xv.y, acc[bi]);
        acc[bi] = fmaf(wv.z, xv.z, acc[bi]); acc[bi] = fmaf(wv.w, xv.w, acc[bi]);
      }
    }
  }
  float bias = 0.f;
#pragma unroll
  for (int d = 0; d < 16; d++) bias += en_s[d] * ldf(bp, (size_t)d * 128 + o, f);
#pragma unroll
  for (int bi = 0; bi < 32; bi++) {
    int b = bg * 32 + bi;
    float v = 1.f / (1.f + expf(-(acc[bi] + bias)));
    if (o < 64) {
      float s = ldf(state, ((size_t)b * Nn + n) * Hh + o, f);
      XC[(size_t)n * BC + b * 66 + 2 + o] = f2bu(v * s);
    } else {
      size_t idx = ((size_t)b * Nn + n) * Hh + (o - 64);
      if (f) ((float*)Rout)[idx] = v; else ((u16*)Rout)[idx] = f2bu(v);
    }
  }
  if (t < 128) {
    int b = t >> 1, c = t & 1;
    XC[(size_t)n * BC + b * 66 + c] = f2bu(ldf(x, ((size_t)b * Nn + n) * 2 + c, f));
  }
}

__global__ __launch_bounds__(256) void update_kernel_fb(
    const u16* __restrict__ XCn, const u16* __restrict__ Y1, const u16* __restrict__ Y2,
    const void* __restrict__ E, const void* __restrict__ W, const void* __restrict__ bp,
    const void* __restrict__ state, const int* __restrict__ flag, void* out) {
  __shared__ float xg[64][208];
  __shared__ float wnc[64][20];
  __shared__ float en_s[16];
  const int f = *flag;
  const int n = blockIdx.x, t = threadIdx.x;
  if (t < 16) en_s[t] = ldf(E, (size_t)n * 16 + t, f);
  for (int j = t; j < 64 * 66; j += 256) {
    int b = j / 66, c = j - b * 66;
    float v0 = bu2f(XCn[(size_t)n * BC + j]);
    xg[b][c] = v0;
    xg[b][66 + c] = bu2f(Y1[(size_t)n * BC + j]);
    xg[b][132 + c] = 2.f * bu2f(Y2[(size_t)n * BC + j]) - v0;
  }
  for (int j = t; j < 64 * 10; j += 256) xg[j / 10][198 + (j % 10)] = 0.f;
  const int o4 = t & 15, kl = t >> 4;
  const int o = t & 63, bg = t >> 6;
  float acc[16];
#pragma unroll
  for (int i = 0; i < 16; i++) acc[i] = 0.f;
  for (int c0 = 0; c0 < 208; c0 += 16) {
    __syncthreads();
    {
      int ki = c0 + kl;
      float a4[4];
#pragma unroll
      for (int j = 0; j < 4; j++) a4[j] = 0.f;
      if (ki < 198) {
#pragma unroll
        for (int d = 0; d < 16; d++) {
          float e = en_s[d];
#pragma unroll
          for (int j = 0; j < 4; j++)
            a4[j] = fmaf(e, ldf(W, (size_t)(d * 198 + ki) * 64 + o4 * 4 + j, f), a4[j]);
        }
      }
#pragma unroll
      for (int j = 0; j < 4; j++) wnc[o4 * 4 + j][kl] = a4[j];
    }
    __syncthreads();
#pragma unroll 1
    for (int kq = 0; kq < 4; kq++) {
      float4 wv = *(const float4*)&wnc[o][kq * 4];
#pragma unroll
      for (int bi = 0; bi < 16; bi++) {
        float4 xv = *(const float4*)&xg[bg * 16 + bi][c0 + kq * 4];
        acc[bi] = fmaf(wv.x, xv.x, acc[bi]); acc[bi] = fmaf(wv.y, xv.y, acc[bi]);
        acc[bi] = fmaf(wv.z, xv.z, acc[bi]); acc[bi] = fmaf(wv.w, xv.w, acc[bi]);
      }
    }
  }
  float bias = 0.f;
#pragma unroll
  for (int d = 0; d < 16; d++) bias += en_s[d] * ldf(bp, (size_t)d * 64 + o, f);
#pragma unroll
  for (int bi = 0; bi < 16; bi++) {
    int b = bg * 16 + bi;
    size_t idx = ((size_t)b * Nn + n) * Hh + o;
    float hc = tanhf(acc[bi] + bias);
    float r = f ? ((const float*)out)[idx] : bu2f(((const u16*)out)[idx]);
    float s = ldf(state, idx, f);
    float v = r * s + (1.f - r) * hc;
    if (f) ((float*)out)[idx] = v; else ((u16*)out)[idx] = f2bu(v);
  }
}

// ---------------------------------------------------------------------------
extern "C" void kernel_launch(void* const* d_in, const int* in_sizes, int n_in,
                              void* d_out, int out_size, void* d_ws, size_t ws_size,
                              hipStream_t stream) {
  const void* x     = d_in[0];
  const void* state = d_in[1];
  const void* E     = d_in[2];
  const void* mask  = d_in[3];
  const void* gW    = d_in[4];
  const void* gb    = d_in[5];
  const void* uW    = d_in[6];
  const void* ub    = d_in[7];
  const int* normalize = (const int*)d_in[8];

  char* w = (char*)d_ws;
  int* flag = (int*)w;
  u16* A   = (u16*)(w + 64);
  u16* Xt  = A + (size_t)Nn * Nn;        // later: XC (candidate, node-major)
  u16* Y1t = Xt + (size_t)Nn * BC;
  u16* Y1  = Y1t + (size_t)Nn * BC;
  u16* Q   = Y1 + (size_t)Nn * BC;       // Y2 / XCt / Y2'
  size_t base = 64 + (size_t)Nn * Nn * 2 + 4 * (size_t)Nn * BC * 2;  // 77,594,688
  size_t wntOff = (base + 255) & ~(size_t)255;

  int cs = 0;
  for (int c = 2048; c >= 64; c >>= 1)
    if (wntOff + (size_t)c * 128 * KP * 2 <= ws_size) { cs = c; break; }
  u16* Wnt = (u16*)(w + wntOff);

  detect_kernel<<<1, 64, 0, stream>>>(E, flag);
  support_kernel<<<Nn, 256, 0, stream>>>(E, mask, normalize, flag, A);
  build_xt_kernel<<<dim3(32, 64), 256, 0, stream>>>(x, state, flag, Xt);

  dim3 g(33, 16);
  gemm_bt<<<g, 256, 0, stream>>>(A, Xt, Y1, Y1t);        // Y1 = A@X   (+Y1t)
  gemm_bt<<<g, 256, 0, stream>>>(A, Y1t, Q, nullptr);    // Y2 = A@Y1

  if (cs) {
    for (int c0 = 0; c0 < Nn; c0 += cs) {
      fold_kernel<<<dim3(cs / 64, 28), 256, 0, stream>>>(E, gW, Wnt, flag, c0, 128);
      avw_gate<<<cs, 256, 0, stream>>>(Y1, Q, x, state, E, Wnt, gb, flag, d_out, Xt, c0);
    }
  } else {
    gate_kernel_fb<<<Nn, 256, 0, stream>>>(Y1, Q, x, state, E, gW, gb, flag, d_out, Xt);
  }

  transpose_kernel<<<dim3(66, 32), 256, 0, stream>>>(Xt, Q);   // XCt
  gemm_bt<<<g, 256, 0, stream>>>(A, Q, Y1, Y1t);         // Y1 = A@XC  (+Y1t)
  gemm_bt<<<g, 256, 0, stream>>>(A, Y1t, Q, nullptr);    // Y2' = A@Y1

  if (cs) {
    for (int c0 = 0; c0 < Nn; c0 += cs) {
      fold_kernel<<<dim3(cs / 64, 28), 256, 0, stream>>>(E, uW, Wnt, flag, c0, 64);
      avw_update<<<cs, 256, 0, stream>>>(Xt, Y1, Q, E, Wnt, ub, state, flag, d_out, c0);
    }
  } else {
    update_kernel_fb<<<Nn, 256, 0, stream>>>(Xt, Y1, Q, E, uW, ub, state, flag, d_out);
  }
}

// Round 6
// 643.725 us; speedup vs baseline: 5.8500x; 1.1172x over previous
//
#include <hip/hip_runtime.h>
#include <hip/hip_bf16.h>
#include <cstdint>
#include <cmath>

typedef unsigned short u16;
typedef __attribute__((ext_vector_type(8))) short bf16x8;
typedef __attribute__((ext_vector_type(4))) float f32x4;

__device__ __forceinline__ float bu2f(u16 u) { return __uint_as_float((unsigned)u << 16); }
__device__ __forceinline__ u16 f2bu(float v) {
  union { __hip_bfloat16 h; u16 u; } c; c.h = __float2bfloat16(v); return c.u;
}
__device__ __forceinline__ float ldf(const void* p, size_t i, int f32) {
  return f32 ? ((const float*)p)[i] : bu2f(((const u16*)p)[i]);
}
__device__ __forceinline__ void gll16(const u16* g, u16* lds) {
  __builtin_amdgcn_global_load_lds((const __attribute__((address_space(1))) unsigned*)g,
                                   (__attribute__((address_space(3))) unsigned*)lds, 16, 0, 0);
}

constexpr int Nn = 2048, Bb = 64, Dd = 16, Cc = 66, Hh = 64, BC = 4224;
constexpr int KP = 224;   // padded ki (198 -> 224 = 7*32)

// ---------------------------------------------------------------------------
__global__ void detect_kernel(const void* __restrict__ E, int* __restrict__ flag) {
  if (threadIdx.x == 0) {
    const unsigned* p = (const unsigned*)E;
    int hits = 0;
    for (int i = 0; i < 64; i++) {
      unsigned ex = (p[i] >> 7) & 0xFF;
      hits += (ex >= 100 && ex <= 140) ? 1 : 0;
    }
    *flag = (hits < 32) ? 1 : 0;   // 1 -> inputs are fp32
  }
}

// ---------------------------------------------------------------------------
// Support, wave-per-row: A[n,:] = softmax(relu(E[n]·E^T)) * mask (+ renorm).
// No LDS, no barriers: 32 scores/lane in regs, shfl_xor reductions.
// ---------------------------------------------------------------------------
__global__ __launch_bounds__(256) void support_v2(
    const void* __restrict__ E, const void* __restrict__ mask,
    const int* __restrict__ normalize, const int* __restrict__ flag,
    u16* __restrict__ A) {
  const int f = *flag;
  const int wave = threadIdx.x >> 6, lane = threadIdx.x & 63;
  const int n = blockIdx.x * 4 + wave;

  float en[16];
  if (f) {
    const float* Ef = (const float*)E;
#pragma unroll
    for (int d = 0; d < 16; d++) en[d] = Ef[(size_t)n * 16 + d];
  } else {
    const u16* Eb = (const u16*)E;
#pragma unroll
    for (int d = 0; d < 16; d++) en[d] = bu2f(Eb[(size_t)n * 16 + d]);
  }

  float s[32];
  if (f) {
    const float* Ef = (const float*)E;
#pragma unroll 8
    for (int k = 0; k < 32; k++) {
      const float* er = &Ef[(size_t)(lane + 64 * k) * 16];
      float4 e0 = *(const float4*)&er[0];
      float4 e1 = *(const float4*)&er[4];
      float4 e2 = *(const float4*)&er[8];
      float4 e3 = *(const float4*)&er[12];
      float a = en[0] * e0.x;
      a = fmaf(en[1], e0.y, a);  a = fmaf(en[2], e0.z, a);  a = fmaf(en[3], e0.w, a);
      a = fmaf(en[4], e1.x, a);  a = fmaf(en[5], e1.y, a);  a = fmaf(en[6], e1.z, a);
      a = fmaf(en[7], e1.w, a);  a = fmaf(en[8], e2.x, a);  a = fmaf(en[9], e2.y, a);
      a = fmaf(en[10], e2.z, a); a = fmaf(en[11], e2.w, a); a = fmaf(en[12], e3.x, a);
      a = fmaf(en[13], e3.y, a); a = fmaf(en[14], e3.z, a); a = fmaf(en[15], e3.w, a);
      s[k] = fmaxf(a, 0.f);
    }
  } else {
    const u16* Eb = (const u16*)E;
#pragma unroll 8
    for (int k = 0; k < 32; k++) {
      const u16* er = &Eb[(size_t)(lane + 64 * k) * 16];
      uint4 u0 = *(const uint4*)&er[0];
      uint4 u1 = *(const uint4*)&er[8];
      unsigned w[8] = {u0.x, u0.y, u0.z, u0.w, u1.x, u1.y, u1.z, u1.w};
      float a = 0.f;
#pragma unroll
      for (int i = 0; i < 8; i++) {
        a = fmaf(en[2 * i], bu2f((u16)(w[i] & 0xffff)), a);
        a = fmaf(en[2 * i + 1], bu2f((u16)(w[i] >> 16)), a);
      }
      s[k] = fmaxf(a, 0.f);
    }
  }

  // wave-wide softmax
  float mx = 0.f;
#pragma unroll
  for (int k = 0; k < 32; k++) mx = fmaxf(mx, s[k]);
#pragma unroll
  for (int off = 1; off < 64; off <<= 1) mx = fmaxf(mx, __shfl_xor(mx, off, 64));
  float sum = 0.f;
#pragma unroll
  for (int k = 0; k < 32; k++) { s[k] = expf(s[k] - mx); sum += s[k]; }
#pragma unroll
  for (int off = 1; off < 64; off <<= 1) sum += __shfl_xor(sum, off, 64);
  float inv = 1.f / sum;

  if (f) {
    const float* Mf = (const float*)mask;
#pragma unroll 8
    for (int k = 0; k < 32; k++)
      s[k] = s[k] * inv * Mf[(size_t)n * Nn + lane + 64 * k];
  } else {
    const u16* Mb = (const u16*)mask;
#pragma unroll 8
    for (int k = 0; k < 32; k++)
      s[k] = s[k] * inv * bu2f(Mb[(size_t)n * Nn + lane + 64 * k]);
  }

  if (*normalize != 0) {
    float mx2 = -1e30f;
#pragma unroll
    for (int k = 0; k < 32; k++) mx2 = fmaxf(mx2, s[k]);
#pragma unroll
    for (int off = 1; off < 64; off <<= 1) mx2 = fmaxf(mx2, __shfl_xor(mx2, off, 64));
    float sm2 = 0.f;
#pragma unroll
    for (int k = 0; k < 32; k++) { s[k] = expf(s[k] - mx2); sm2 += s[k]; }
#pragma unroll
    for (int off = 1; off < 64; off <<= 1) sm2 += __shfl_xor(sm2, off, 64);
    float inv2 = 1.f / sm2;
#pragma unroll
    for (int k = 0; k < 32; k++) s[k] *= inv2;
  }

#pragma unroll
  for (int k = 0; k < 32; k++)
    A[(size_t)n * Nn + lane + 64 * k] = f2bu(s[k]);
}

// ---------------------------------------------------------------------------
__global__ __launch_bounds__(256) void build_xt_kernel(
    const void* __restrict__ x, const void* __restrict__ state,
    const int* __restrict__ flag, u16* __restrict__ Xt) {
  __shared__ float sx[66][65];
  int f = *flag;
  int m0 = blockIdx.x * 64, b = blockIdx.y;
  int t = threadIdx.x;
  {
    int cl = t & 63, mg = t >> 6;
    for (int cb = 0; cb < 2; cb++) {
      int c = cb * 64 + cl;
      if (c < 66)
        for (int m = mg; m < 64; m += 4)
          sx[c][m] = (c < 2) ? ldf(x, ((size_t)b * Nn + m0 + m) * 2 + c, f)
                             : ldf(state, ((size_t)b * Nn + m0 + m) * Hh + (c - 2), f);
    }
  }
  __syncthreads();
  for (int cb = 0; cb < 2; cb++) {
    int ch = t >> 2;
    int c = cb * 64 + ch;
    if (c < 66 && (cb == 0 || ch < 2)) {
      int mq = t & 3;
      __align__(16) u16 tmp[16];
#pragma unroll
      for (int i = 0; i < 16; i++) tmp[i] = f2bu(sx[c][mq * 16 + i]);
      *(uint4*)&Xt[(size_t)(b * 66 + c) * 2048 + m0 + mq * 16] = *(uint4*)&tmp[0];
      *(uint4*)&Xt[(size_t)(b * 66 + c) * 2048 + m0 + mq * 16 + 8] = *(uint4*)&tmp[8];
    }
  }
}

// ---------------------------------------------------------------------------
__global__ __launch_bounds__(256) void gemm_bt(
    const u16* __restrict__ A, const u16* __restrict__ Bt,
    u16* __restrict__ C, u16* __restrict__ Ct) {
  __shared__ __align__(16) u16 As[128 * 32];
  __shared__ __align__(16) u16 Bs[128 * 32];
  const int t = threadIdx.x;
  const int wave = t >> 6, lane = t & 63;
  const int bm = blockIdx.y * 128, bj = blockIdx.x * 128;
  const int wm = (wave >> 1) * 64, wj = (wave & 1) * 64;
  const int lr = lane >> 2;
  const int gc = (lane & 3) ^ (lr & 3);
  const int ln = lane & 15, q = lane >> 4;
  const int sw = ((q ^ (ln & 3)) << 3);

  f32x4 acc[4][4];
#pragma unroll
  for (int i = 0; i < 4; i++)
#pragma unroll
    for (int j = 0; j < 4; j++) acc[i][j] = (f32x4){0.f, 0.f, 0.f, 0.f};

  for (int k0 = 0; k0 < 2048; k0 += 32) {
#pragma unroll
    for (int p = 0; p < 2; p++) {
      int rb = wave * 32 + p * 16;
      gll16(&A[(size_t)(bm + rb + lr) * 2048 + k0 + gc * 8], &As[rb * 32]);
      gll16(&Bt[(size_t)(bj + rb + lr) * 2048 + k0 + gc * 8], &Bs[rb * 32]);
    }
    __syncthreads();
    bf16x8 af[4], bfr[4];
#pragma unroll
    for (int i = 0; i < 4; i++) af[i] = *(const bf16x8*)&As[(wm + i * 16 + ln) * 32 + sw];
#pragma unroll
    for (int j = 0; j < 4; j++) bfr[j] = *(const bf16x8*)&Bs[(wj + j * 16 + ln) * 32 + sw];
#pragma unroll
    for (int i = 0; i < 4; i++)
#pragma unroll
      for (int j = 0; j < 4; j++)
        acc[i][j] = __builtin_amdgcn_mfma_f32_16x16x32_bf16(af[i], bfr[j], acc[i][j], 0, 0, 0);
    __syncthreads();
  }
#pragma unroll
  for (int i = 0; i < 4; i++) {
    int mg = bm + wm + i * 16 + q * 4;
#pragma unroll
    for (int j = 0; j < 4; j++) {
      int jg = bj + wj + j * 16 + ln;
      f32x4 v = acc[i][j];
      u16 h0 = f2bu(v[0]), h1 = f2bu(v[1]), h2 = f2bu(v[2]), h3 = f2bu(v[3]);
      if (Ct) {
        uint2 pk = make_uint2((unsigned)h0 | ((unsigned)h1 << 16),
                              (unsigned)h2 | ((unsigned)h3 << 16));
        *(uint2*)&Ct[(size_t)jg * 2048 + mg] = pk;
      }
      C[(size_t)(mg + 0) * 4224 + jg] = h0;
      C[(size_t)(mg + 1) * 4224 + jg] = h1;
      C[(size_t)(mg + 2) * 4224 + jg] = h2;
      C[(size_t)(mg + 3) * 4224 + jg] = h3;
    }
  }
}

// ---------------------------------------------------------------------------
__global__ __launch_bounds__(256) void transpose_kernel(
    const u16* __restrict__ S, u16* __restrict__ D) {
  __shared__ u16 sm[64][70];
  int j0 = blockIdx.x * 64, m0 = blockIdx.y * 64;
  int t = threadIdx.x;
  {
    int c = t & 63, r0 = t >> 6;
    for (int r = r0; r < 64; r += 4)
      sm[r][c] = S[(size_t)(m0 + r) * 4224 + j0 + c];
  }
  __syncthreads();
  {
    int jl = t >> 2, mq = t & 3;
    __align__(16) u16 tmp[16];
#pragma unroll
    for (int i = 0; i < 16; i++) tmp[i] = sm[mq * 16 + i][jl];
    *(uint4*)&D[(size_t)(j0 + jl) * 2048 + m0 + mq * 16] = *(uint4*)&tmp[0];
    *(uint4*)&D[(size_t)(j0 + jl) * 2048 + m0 + mq * 16 + 8] = *(uint4*)&tmp[8];
  }
}

// ---------------------------------------------------------------------------
// Fold: Wnt[n_rel][o][KP] (bf16) = sum_d E[n,d] * W[d][ki][o], ki padded ->0.
// ---------------------------------------------------------------------------
__global__ __launch_bounds__(256) void fold_kernel(
    const void* __restrict__ E, const void* __restrict__ W,
    u16* __restrict__ Wnt, const int* __restrict__ flag, int n0, int O) {
  __shared__ float Es[64][16];
  const int f = *flag;
  const int t = threadIdx.x;
  const int nb = n0 + blockIdx.x * 64;
  const int ki0 = blockIdx.y * 8;
  for (int j = t; j < 1024; j += 256)
    Es[j >> 4][j & 15] = ldf(E, (size_t)(nb + (j >> 4)) * 16 + (j & 15), f);

  const int o = t & (O - 1);
  const int tpn = 256 / O;
  const int nh = t / O;
  const int NPT = 64 / tpn;

  float wv[128];
  if (f) {
    const float* Wf = (const float*)W;
#pragma unroll
    for (int d = 0; d < 16; d++)
#pragma unroll
      for (int i = 0; i < 8; i++) {
        int ki = ki0 + i;
        wv[d * 8 + i] = (ki < 198) ? Wf[((size_t)d * 198 + ki) * O + o] : 0.f;
      }
  } else {
    const u16* Wb = (const u16*)W;
#pragma unroll
    for (int d = 0; d < 16; d++)
#pragma unroll
      for (int i = 0; i < 8; i++) {
        int ki = ki0 + i;
        wv[d * 8 + i] = (ki < 198) ? bu2f(Wb[((size_t)d * 198 + ki) * O + o]) : 0.f;
      }
  }
  __syncthreads();

  for (int r = 0; r < NPT; r++) {
    int nl = nh * NPT + r;
    float en[16];
#pragma unroll
    for (int d = 0; d < 16; d++) en[d] = Es[nl][d];
    float a8[8];
#pragma unroll
    for (int i = 0; i < 8; i++) a8[i] = 0.f;
#pragma unroll
    for (int d = 0; d < 16; d++)
#pragma unroll
      for (int i = 0; i < 8; i++) a8[i] = fmaf(en[d], wv[d * 8 + i], a8[i]);
    unsigned pw[4];
#pragma unroll
    for (int i = 0; i < 4; i++)
      pw[i] = (unsigned)f2bu(a8[2 * i]) | ((unsigned)f2bu(a8[2 * i + 1]) << 16);
    *(uint4*)&Wnt[((size_t)(blockIdx.x * 64 + nl) * O + o) * KP + ki0] =
        make_uint4(pw[0], pw[1], pw[2], pw[3]);
  }
}

// ---------------------------------------------------------------------------
// MFMA per-node einsum, gate (O=128)
// ---------------------------------------------------------------------------
__global__ __launch_bounds__(256) void avw_gate(
    const u16* __restrict__ Y1, const u16* __restrict__ Y2,
    const void* __restrict__ x, const void* __restrict__ state,
    const void* __restrict__ E, const u16* __restrict__ Wnt,
    const void* __restrict__ bp, const int* __restrict__ flag,
    void* Rout, u16* __restrict__ XC, int n0) {
  __shared__ unsigned xg32[64][116];
  __shared__ float en_s[16];
  const int f = *flag;
  const int bx = blockIdx.x;
  const int n = n0 + bx;
  const int t = threadIdx.x;
  if (t < 16) en_s[t] = ldf(E, (size_t)n * 16 + t, f);

  const unsigned* Y1u = (const unsigned*)(Y1 + (size_t)n * BC);
  const unsigned* Y2u = (const unsigned*)(Y2 + (size_t)n * BC);
  for (int j = t; j < 64 * 33; j += 256) {
    int b = j / 33, cp = j - b * 33, c = cp * 2;
    float x0, x1;
    if (cp == 0) {
      x0 = ldf(x, ((size_t)b * Nn + n) * 2 + 0, f);
      x1 = ldf(x, ((size_t)b * Nn + n) * 2 + 1, f);
    } else {
      x0 = ldf(state, ((size_t)b * Nn + n) * Hh + (c - 2), f);
      x1 = ldf(state, ((size_t)b * Nn + n) * Hh + (c - 1), f);
    }
    unsigned y1 = Y1u[b * 33 + cp];
    unsigned y2 = Y2u[b * 33 + cp];
    float t20 = 2.f * bu2f((u16)(y2 & 0xffff)) - x0;
    float t21 = 2.f * bu2f((u16)(y2 >> 16)) - x1;
    xg32[b][cp]      = (unsigned)f2bu(x0) | ((unsigned)f2bu(x1) << 16);
    xg32[b][33 + cp] = y1;
    xg32[b][66 + cp] = (unsigned)f2bu(t20) | ((unsigned)f2bu(t21) << 16);
  }
  for (int j = t; j < 64 * 17; j += 256) xg32[j / 17][99 + (j - (j / 17) * 17)] = 0u;
  __syncthreads();

  const int wave = t >> 6, lane = t & 63;
  const int ln = lane & 15, q = lane >> 4;
  f32x4 acc[4][2];
#pragma unroll
  for (int i = 0; i < 4; i++) { acc[i][0] = (f32x4){0,0,0,0}; acc[i][1] = (f32x4){0,0,0,0}; }

  const u16* Wrow = Wnt + (size_t)bx * 128 * KP;
  const u16* xg16 = (const u16*)&xg32[0][0];
  for (int k0 = 0; k0 < KP; k0 += 32) {
    bf16x8 bfr[2];
#pragma unroll
    for (int oi = 0; oi < 2; oi++) {
      int o = (wave * 2 + oi) * 16 + ln;
      bfr[oi] = *(const bf16x8*)&Wrow[(size_t)o * KP + k0 + q * 8];
    }
#pragma unroll
    for (int mt = 0; mt < 4; mt++) {
      bf16x8 af = *(const bf16x8*)&xg16[(mt * 16 + ln) * 232 + k0 + q * 8];
      acc[mt][0] = __builtin_amdgcn_mfma_f32_16x16x32_bf16(af, bfr[0], acc[mt][0], 0, 0, 0);
      acc[mt][1] = __builtin_amdgcn_mfma_f32_16x16x32_bf16(af, bfr[1], acc[mt][1], 0, 0, 0);
    }
  }

  float bias[2];
#pragma unroll
  for (int oi = 0; oi < 2; oi++) {
    int o = (wave * 2 + oi) * 16 + ln;
    float s = 0.f;
#pragma unroll
    for (int d = 0; d < 16; d++) s += en_s[d] * ldf(bp, (size_t)d * 128 + o, f);
    bias[oi] = s;
  }
#pragma unroll
  for (int mt = 0; mt < 4; mt++)
#pragma unroll
    for (int oi = 0; oi < 2; oi++) {
      int o = (wave * 2 + oi) * 16 + ln;
#pragma unroll
      for (int r = 0; r < 4; r++) {
        int b = mt * 16 + q * 4 + r;
        float v = 1.f / (1.f + expf(-(acc[mt][oi][r] + bias[oi])));
        if (o < 64) {
          float s = ldf(state, ((size_t)b * Nn + n) * Hh + o, f);
          XC[(size_t)n * BC + b * 66 + 2 + o] = f2bu(v * s);
        } else {
          size_t idx = ((size_t)b * Nn + n) * Hh + (o - 64);
          if (f) ((float*)Rout)[idx] = v; else ((u16*)Rout)[idx] = f2bu(v);
        }
      }
    }
  if (t < 128) {
    int b = t >> 1, c = t & 1;
    XC[(size_t)n * BC + b * 66 + c] = f2bu(ldf(x, ((size_t)b * Nn + n) * 2 + c, f));
  }
}

// ---------------------------------------------------------------------------
// MFMA per-node einsum, update (O=64)
// ---------------------------------------------------------------------------
__global__ __launch_bounds__(256) void avw_update(
    const u16* __restrict__ XCn, const u16* __restrict__ Y1, const u16* __restrict__ Y2,
    const void* __restrict__ E, const u16* __restrict__ Wnt,
    const void* __restrict__ bp, const void* __restrict__ state,
    const int* __restrict__ flag, void* out, int n0) {
  __shared__ unsigned xg32[64][116];
  __shared__ float en_s[16];
  const int f = *flag;
  const int bx = blockIdx.x;
  const int n = n0 + bx;
  const int t = threadIdx.x;
  if (t < 16) en_s[t] = ldf(E, (size_t)n * 16 + t, f);

  const unsigned* XCu = (const unsigned*)(XCn + (size_t)n * BC);
  const unsigned* Y1u = (const unsigned*)(Y1 + (size_t)n * BC);
  const unsigned* Y2u = (const unsigned*)(Y2 + (size_t)n * BC);
  for (int j = t; j < 64 * 33; j += 256) {
    int b = j / 33, cp = j - b * 33;
    unsigned x01 = XCu[b * 33 + cp];
    unsigned y1 = Y1u[b * 33 + cp];
    unsigned y2 = Y2u[b * 33 + cp];
    float x0 = bu2f((u16)(x01 & 0xffff)), x1 = bu2f((u16)(x01 >> 16));
    float t20 = 2.f * bu2f((u16)(y2 & 0xffff)) - x0;
    float t21 = 2.f * bu2f((u16)(y2 >> 16)) - x1;
    xg32[b][cp]      = x01;
    xg32[b][33 + cp] = y1;
    xg32[b][66 + cp] = (unsigned)f2bu(t20) | ((unsigned)f2bu(t21) << 16);
  }
  for (int j = t; j < 64 * 17; j += 256) xg32[j / 17][99 + (j - (j / 17) * 17)] = 0u;
  __syncthreads();

  const int wave = t >> 6, lane = t & 63;
  const int ln = lane & 15, q = lane >> 4;
  f32x4 acc[4];
#pragma unroll
  for (int i = 0; i < 4; i++) acc[i] = (f32x4){0, 0, 0, 0};

  const u16* Wrow = Wnt + (size_t)bx * 64 * KP;
  const u16* xg16 = (const u16*)&xg32[0][0];
  const int o = wave * 16 + ln;
  for (int k0 = 0; k0 < KP; k0 += 32) {
    bf16x8 bfr = *(const bf16x8*)&Wrow[(size_t)o * KP + k0 + q * 8];
#pragma unroll
    for (int mt = 0; mt < 4; mt++) {
      bf16x8 af = *(const bf16x8*)&xg16[(mt * 16 + ln) * 232 + k0 + q * 8];
      acc[mt] = __builtin_amdgcn_mfma_f32_16x16x32_bf16(af, bfr, acc[mt], 0, 0, 0);
    }
  }

  float bias = 0.f;
#pragma unroll
  for (int d = 0; d < 16; d++) bias += en_s[d] * ldf(bp, (size_t)d * 64 + o, f);
#pragma unroll
  for (int mt = 0; mt < 4; mt++)
#pragma unroll
    for (int r = 0; r < 4; r++) {
      int b = mt * 16 + q * 4 + r;
      size_t idx = ((size_t)b * Nn + n) * Hh + o;
      float hc = tanhf(acc[mt][r] + bias);
      float rr = f ? ((const float*)out)[idx] : bu2f(((const u16*)out)[idx]);
      float s = ldf(state, idx, f);
      float v = rr * s + (1.f - rr) * hc;
      if (f) ((float*)out)[idx] = v; else ((u16*)out)[idx] = f2bu(v);
    }
}

// ---------------------------------------------------------------------------
// Fallback gate/update for tiny workspaces
// ---------------------------------------------------------------------------
__global__ __launch_bounds__(256) void gate_kernel_fb(
    const u16* __restrict__ Y1, const u16* __restrict__ Y2,
    const void* __restrict__ x, const void* __restrict__ state,
    const void* __restrict__ E, const void* __restrict__ W, const void* __restrict__ bp,
    const int* __restrict__ flag, void* Rout, u16* __restrict__ XC) {
  __shared__ float xg[64][208];
  __shared__ float wnc[128][20];
  __shared__ float en_s[16];
  const int f = *flag;
  const int n = blockIdx.x, t = threadIdx.x;
  if (t < 16) en_s[t] = ldf(E, (size_t)n * 16 + t, f);
  for (int j = t; j < 64 * 66; j += 256) {
    int b = j / 66, c = j - b * 66;
    float v0 = (c < 2) ? ldf(x, ((size_t)b * Nn + n) * 2 + c, f)
                       : ldf(state, ((size_t)b * Nn + n) * Hh + (c - 2), f);
    xg[b][c] = v0;
    xg[b][66 + c] = bu2f(Y1[(size_t)n * BC + j]);
    xg[b][132 + c] = 2.f * bu2f(Y2[(size_t)n * BC + j]) - v0;
  }
  for (int j = t; j < 64 * 10; j += 256) xg[j / 10][198 + (j % 10)] = 0.f;
  const int o8 = t & 15, kl = t >> 4;
  const int o = t & 127, bg = t >> 7;
  float acc[32];
#pragma unroll
  for (int i = 0; i < 32; i++) acc[i] = 0.f;
  for (int c0 = 0; c0 < 208; c0 += 16) {
    __syncthreads();
    {
      int ki = c0 + kl;
      float a8[8];
#pragma unroll
      for (int j = 0; j < 8; j++) a8[j] = 0.f;
      if (ki < 198) {
#pragma unroll
        for (int d = 0; d < 16; d++) {
          float e = en_s[d];
#pragma unroll
          for (int j = 0; j < 8; j++)
            a8[j] = fmaf(e, ldf(W, (size_t)(d * 198 + ki) * 128 + o8 * 8 + j, f), a8[j]);
        }
      }
#pragma unroll
      for (int j = 0; j < 8; j++) wnc[o8 * 8 + j][kl] = a8[j];
    }
    __syncthreads();
#pragma unroll 1
    for (int kq = 0; kq < 4; kq++) {
      float4 wv = *(const float4*)&wnc[o][kq * 4];
#pragma unroll
      for (int bi = 0; bi < 32; bi++) {
        float4 xv = *(const float4*)&xg[bg * 32 + bi][c0 + kq * 4];
        acc[bi] = fmaf(wv.x, xv.x, acc[bi]); acc[bi] = fmaf(wv.y, xv.y, acc[bi]);
        acc[bi] = fmaf(wv.z, xv.z, acc[bi]); acc[bi] = fmaf(wv.w, xv.w, acc[bi]);
      }
    }
  }
  float bias = 0.f;
#pragma unroll
  for (int d = 0; d < 16; d++) bias += en_s[d] * ldf(bp, (size_t)d * 128 + o, f);
#pragma unroll
  for (int bi = 0; bi < 32; bi++) {
    int b = bg * 32 + bi;
    float v = 1.f / (1.f + expf(-(acc[bi] + bias)));
    if (o < 64) {
      float s = ldf(state, ((size_t)b * Nn + n) * Hh + o, f);
      XC[(size_t)n * BC + b * 66 + 2 + o] = f2bu(v * s);
    } else {
      size_t idx = ((size_t)b * Nn + n) * Hh + (o - 64);
      if (f) ((float*)Rout)[idx] = v; else ((u16*)Rout)[idx] = f2bu(v);
    }
  }
  if (t < 128) {
    int b = t >> 1, c = t & 1;
    XC[(size_t)n * BC + b * 66 + c] = f2bu(ldf(x, ((size_t)b * Nn + n) * 2 + c, f));
  }
}

__global__ __launch_bounds__(256) void update_kernel_fb(
    const u16* __restrict__ XCn, const u16* __restrict__ Y1, const u16* __restrict__ Y2,
    const void* __restrict__ E, const void* __restrict__ W, const void* __restrict__ bp,
    const void* __restrict__ state, const int* __restrict__ flag, void* out) {
  __shared__ float xg[64][208];
  __shared__ float wnc[64][20];
  __shared__ float en_s[16];
  const int f = *flag;
  const int n = blockIdx.x, t = threadIdx.x;
  if (t < 16) en_s[t] = ldf(E, (size_t)n * 16 + t, f);
  for (int j = t; j < 64 * 66; j += 256) {
    int b = j / 66, c = j - b * 66;
    float v0 = bu2f(XCn[(size_t)n * BC + j]);
    xg[b][c] = v0;
    xg[b][66 + c] = bu2f(Y1[(size_t)n * BC + j]);
    xg[b][132 + c] = 2.f * bu2f(Y2[(size_t)n * BC + j]) - v0;
  }
  for (int j = t; j < 64 * 10; j += 256) xg[j / 10][198 + (j % 10)] = 0.f;
  const int o4 = t & 15, kl = t >> 4;
  const int o = t & 63, bg = t >> 6;
  float acc[16];
#pragma unroll
  for (int i = 0; i < 16; i++) acc[i] = 0.f;
  for (int c0 = 0; c0 < 208; c0 += 16) {
    __syncthreads();
    {
      int ki = c0 + kl;
      float a4[4];
#pragma unroll
      for (int j = 0; j < 4; j++) a4[j] = 0.f;
      if (ki < 198) {
#pragma unroll
        for (int d = 0; d < 16; d++) {
          float e = en_s[d];
#pragma unroll
          for (int j = 0; j < 4; j++)
            a4[j] = fmaf(e, ldf(W, (size_t)(d * 198 + ki) * 64 + o4 * 4 + j, f), a4[j]);
        }
      }
#pragma unroll
      for (int j = 0; j < 4; j++) wnc[o4 * 4 + j][kl] = a4[j];
    }
    __syncthreads();
#pragma unroll 1
    for (int kq = 0; kq < 4; kq++) {
      float4 wv = *(const float4*)&wnc[o][kq * 4];
#pragma unroll
      for (int bi = 0; bi < 16; bi++) {
        float4 xv = *(const float4*)&xg[bg * 16 + bi][c0 + kq * 4];
        acc[bi] = fmaf(wv.x, xv.x, acc[bi]); acc[bi] = fmaf(wv.y, xv.y, acc[bi]);
        acc[bi] = fmaf(wv.z, xv.z, acc[bi]); acc[bi] = fmaf(wv.w, xv.w, acc[bi]);
      }
    }
  }
  float bias = 0.f;
#pragma unroll
  for (int d = 0; d < 16; d++) bias += en_s[d] * ldf(bp, (size_t)d * 64 + o, f);
#pragma unroll
  for (int bi = 0; bi < 16; bi++) {
    int b = bg * 16 + bi;
    size_t idx = ((size_t)b * Nn + n) * Hh + o;
    float hc = tanhf(acc[bi] + bias);
    float r = f ? ((const float*)out)[idx] : bu2f(((const u16*)out)[idx]);
    float s = ldf(state, idx, f);
    float v = r * s + (1.f - r) * hc;
    if (f) ((float*)out)[idx] = v; else ((u16*)out)[idx] = f2bu(v);
  }
}

// ---------------------------------------------------------------------------
extern "C" void kernel_launch(void* const* d_in, const int* in_sizes, int n_in,
                              void* d_out, int out_size, void* d_ws, size_t ws_size,
                              hipStream_t stream) {
  const void* x     = d_in[0];
  const void* state = d_in[1];
  const void* E     = d_in[2];
  const void* mask  = d_in[3];
  const void* gW    = d_in[4];
  const void* gb    = d_in[5];
  const void* uW    = d_in[6];
  const void* ub    = d_in[7];
  const int* normalize = (const int*)d_in[8];

  char* w = (char*)d_ws;
  int* flag = (int*)w;
  u16* A   = (u16*)(w + 64);
  u16* Xt  = A + (size_t)Nn * Nn;        // later: XC (candidate, node-major)
  u16* Y1t = Xt + (size_t)Nn * BC;
  u16* Y1  = Y1t + (size_t)Nn * BC;
  u16* Q   = Y1 + (size_t)Nn * BC;       // Y2 / XCt / Y2'
  size_t base = 64 + (size_t)Nn * Nn * 2 + 4 * (size_t)Nn * BC * 2;
  size_t wntOff = (base + 255) & ~(size_t)255;

  int cs = 0;
  for (int c = 2048; c >= 64; c >>= 1)
    if (wntOff + (size_t)c * 128 * KP * 2 <= ws_size) { cs = c; break; }
  u16* Wnt = (u16*)(w + wntOff);

  detect_kernel<<<1, 64, 0, stream>>>(E, flag);
  support_v2<<<Nn / 4, 256, 0, stream>>>(E, mask, normalize, flag, A);
  build_xt_kernel<<<dim3(32, 64), 256, 0, stream>>>(x, state, flag, Xt);

  dim3 g(33, 16);
  gemm_bt<<<g, 256, 0, stream>>>(A, Xt, Y1, Y1t);        // Y1 = A@X   (+Y1t)
  gemm_bt<<<g, 256, 0, stream>>>(A, Y1t, Q, nullptr);    // Y2 = A@Y1

  if (cs) {
    for (int c0 = 0; c0 < Nn; c0 += cs) {
      fold_kernel<<<dim3(cs / 64, 28), 256, 0, stream>>>(E, gW, Wnt, flag, c0, 128);
      avw_gate<<<cs, 256, 0, stream>>>(Y1, Q, x, state, E, Wnt, gb, flag, d_out, Xt, c0);
    }
  } else {
    gate_kernel_fb<<<Nn, 256, 0, stream>>>(Y1, Q, x, state, E, gW, gb, flag, d_out, Xt);
  }

  transpose_kernel<<<dim3(66, 32), 256, 0, stream>>>(Xt, Q);   // XCt
  gemm_bt<<<g, 256, 0, stream>>>(A, Q, Y1, Y1t);         // Y1 = A@XC  (+Y1t)
  gemm_bt<<<g, 256, 0, stream>>>(A, Y1t, Q, nullptr);    // Y2' = A@Y1

  if (cs) {
    for (int c0 = 0; c0 < Nn; c0 += cs) {
      fold_kernel<<<dim3(cs / 64, 28), 256, 0, stream>>>(E, uW, Wnt, flag, c0, 64);
      avw_update<<<cs, 256, 0, stream>>>(Xt, Y1, Q, E, Wnt, ub, state, flag, d_out, c0);
    }
  } else {
    update_kernel_fb<<<Nn, 256, 0, stream>>>(Xt, Y1, Q, E, uW, ub, state, flag, d_out);
  }
}